// Round 1
// baseline (2762.419 us; speedup 1.0000x reference)
//
#include <hip/hip_runtime.h>
#include <hip/hip_bf16.h>

#define IN_DIM 1024
#define HID 512
#define OUTD 256

// ---------------- degree / norm kernels ----------------

__global__ void deg_kernel(const int* __restrict__ src, const int* __restrict__ dst,
                           float* __restrict__ dout, float* __restrict__ din, int E) {
    int i = blockIdx.x * blockDim.x + threadIdx.x;
    if (i < E) {
        atomicAdd(&dout[src[i]], 1.0f);
        atomicAdd(&din[dst[i]], 1.0f);
    }
}

__global__ void invsqrt_kernel(float* __restrict__ dout, float* __restrict__ din, int n) {
    int i = blockIdx.x * blockDim.x + threadIdx.x;
    if (i < n) {
        dout[i] = rsqrtf(fmaxf(dout[i], 1.0f));
        din[i]  = rsqrtf(fmaxf(din[i],  1.0f));
    }
}

// ---------------- fp32 tiled GEMM: C[M,Nc] = (rs ⊙ A[M,K]) @ B[K,Nc] ----------------
// BM=BN=64, BK=16, 256 threads, 4x4 micro-tile per thread.

#define BM 64
#define BN 64
#define BK 16

__global__ __launch_bounds__(256) void sgemm_scaled(
    const float* __restrict__ A, const float* __restrict__ B,
    const float* __restrict__ row_scale, float* __restrict__ C,
    int M, int K, int Nc)
{
    __shared__ float As[BK][BM + 4];   // +4 pad keeps 16B alignment, kills store conflicts
    __shared__ float Bs[BK][BN];

    const int tid = threadIdx.x;
    const int n0 = blockIdx.x * BN;
    const int m0 = blockIdx.y * BM;
    const int tx = tid & 15;        // 0..15 -> 4 cols each
    const int ty = tid >> 4;        // 0..15 -> 4 rows each

    // A staging: thread loads one float4; row = tid/4 (0..63), k-quad = tid%4
    const int ar  = tid >> 2;
    const int akq = tid & 3;
    const float rs = row_scale ? row_scale[m0 + ar] : 1.0f;

    // B staging: thread loads one float4; k-row = tid/16 (0..15), col-quad = tid%16
    const int bkr = tid >> 4;
    const int bnc = tid & 15;

    float acc[4][4] = {};

    const int nk = K / BK;
    for (int kt = 0; kt < nk; ++kt) {
        const int k0 = kt * BK;

        float4 av = *reinterpret_cast<const float4*>(
            &A[(size_t)(m0 + ar) * K + k0 + akq * 4]);
        As[akq * 4 + 0][ar] = av.x * rs;
        As[akq * 4 + 1][ar] = av.y * rs;
        As[akq * 4 + 2][ar] = av.z * rs;
        As[akq * 4 + 3][ar] = av.w * rs;

        float4 bv = *reinterpret_cast<const float4*>(
            &B[(size_t)(k0 + bkr) * Nc + n0 + bnc * 4]);
        *reinterpret_cast<float4*>(&Bs[bkr][bnc * 4]) = bv;

        __syncthreads();

        #pragma unroll
        for (int k = 0; k < BK; ++k) {
            float4 aq = *reinterpret_cast<const float4*>(&As[k][ty * 4]);
            float4 bq = *reinterpret_cast<const float4*>(&Bs[k][tx * 4]);
            acc[0][0] += aq.x * bq.x; acc[0][1] += aq.x * bq.y;
            acc[0][2] += aq.x * bq.z; acc[0][3] += aq.x * bq.w;
            acc[1][0] += aq.y * bq.x; acc[1][1] += aq.y * bq.y;
            acc[1][2] += aq.y * bq.z; acc[1][3] += aq.y * bq.w;
            acc[2][0] += aq.z * bq.x; acc[2][1] += aq.z * bq.y;
            acc[2][2] += aq.z * bq.z; acc[2][3] += aq.z * bq.w;
            acc[3][0] += aq.w * bq.x; acc[3][1] += aq.w * bq.y;
            acc[3][2] += aq.w * bq.z; acc[3][3] += aq.w * bq.w;
        }

        __syncthreads();
    }

    #pragma unroll
    for (int i = 0; i < 4; ++i) {
        float4 cv = make_float4(acc[i][0], acc[i][1], acc[i][2], acc[i][3]);
        *reinterpret_cast<float4*>(
            &C[(size_t)(m0 + ty * 4 + i) * Nc + n0 + tx * 4]) = cv;
    }
}

// ---------------- edge scatter-add: agg[dst] += X[src] ----------------

template<int DIM>
__global__ __launch_bounds__(256) void scatter_add(
    const int* __restrict__ src, const int* __restrict__ dst,
    const float* __restrict__ X, float* __restrict__ agg, int E)
{
    int e = blockIdx.x;
    int s = src[e], d = dst[e];
    const float* xr = X + (size_t)s * DIM;
    float* ar = agg + (size_t)d * DIM;
    #pragma unroll
    for (int j = threadIdx.x; j < DIM; j += 256)
        atomicAdd(&ar[j], xr[j]);
}

// ---------------- fused: v = agg*isi + b1; v = elu(v); out = v*iso ----------------

__global__ void elu_scale(const float* __restrict__ agg, const float* __restrict__ isi,
                          const float* __restrict__ iso, const float* __restrict__ b1,
                          float* __restrict__ out, int total)
{
    int i = blockIdx.x * blockDim.x + threadIdx.x;
    if (i < total) {
        int n = i >> 9;       // / HID(512)
        int j = i & 511;
        float v = agg[i] * isi[n] + b1[j];
        v = v > 0.f ? v : expm1f(v);
        out[i] = v * iso[n];
    }
}

// ---------------- finalize: out = out*isi + b2 ----------------

__global__ void finalize(float* __restrict__ out, const float* __restrict__ isi,
                         const float* __restrict__ b2, int total)
{
    int i = blockIdx.x * blockDim.x + threadIdx.x;
    if (i < total) {
        int n = i >> 8;       // / OUTD(256)
        int j = i & 255;
        out[i] = out[i] * isi[n] + b2[j];
    }
}

// ---------------- launch ----------------

extern "C" void kernel_launch(void* const* d_in, const int* in_sizes, int n_in,
                              void* d_out, int out_size, void* d_ws, size_t ws_size,
                              hipStream_t stream) {
    const float* h  = (const float*)d_in[0];
    const float* W1 = (const float*)d_in[1];
    const float* b1 = (const float*)d_in[2];
    const float* W2 = (const float*)d_in[3];
    const float* b2 = (const float*)d_in[4];
    const int*   src = (const int*)d_in[5];
    const int*   dst = (const int*)d_in[6];

    const int N = in_sizes[0] / IN_DIM;   // 65536
    const int E = in_sizes[5];            // 524288
    float* out = (float*)d_out;

    float* iso  = (float*)d_ws;                    // N
    float* isi  = iso + N;                         // N
    float* bufA = isi + N;                         // N*HID (GEMM1 out; later ELU out)
    float* bufB = bufA + (size_t)N * HID;          // N*HID (agg1; later GEMM2 out)

    hipMemsetAsync(iso,  0, sizeof(float) * (size_t)2 * N, stream);
    hipMemsetAsync(bufB, 0, sizeof(float) * (size_t)N * HID, stream);
    hipMemsetAsync(out,  0, sizeof(float) * (size_t)N * OUTD, stream);

    deg_kernel<<<(E + 255) / 256, 256, 0, stream>>>(src, dst, iso, isi, E);
    invsqrt_kernel<<<(N + 255) / 256, 256, 0, stream>>>(iso, isi, N);

    // Layer 1: X1 = (iso ⊙ h) @ W1
    dim3 g1(HID / BN, N / BM);
    sgemm_scaled<<<g1, 256, 0, stream>>>(h, W1, iso, bufA, N, IN_DIM, HID);
    scatter_add<HID><<<E, 256, 0, stream>>>(src, dst, bufA, bufB, E);
    elu_scale<<<((size_t)N * HID + 255) / 256, 256, 0, stream>>>(bufB, isi, iso, b1, bufA, N * HID);

    // Layer 2: X2 = x1s @ W2  (iso already folded into x1s by elu_scale)
    dim3 g2(OUTD / BN, N / BM);
    sgemm_scaled<<<g2, 256, 0, stream>>>(bufA, W2, nullptr, bufB, N, HID, OUTD);
    scatter_add<OUTD><<<E, 256, 0, stream>>>(src, dst, bufB, out, E);
    finalize<<<(N * OUTD + 255) / 256, 256, 0, stream>>>(out, isi, b2, N * OUTD);
}

// Round 2
// 1660.043 us; speedup vs baseline: 1.6641x; 1.6641x over previous
//
#include <hip/hip_runtime.h>
#include <hip/hip_bf16.h>

#define IN_DIM 1024
#define HID 512
#define OUTD 256

typedef __attribute__((ext_vector_type(8))) short short8;
typedef __attribute__((ext_vector_type(4))) float f32x4;

// ---------------- helpers ----------------

__device__ inline unsigned short f2bf(float f) {
    union { float f; unsigned u; } v; v.f = f;
    unsigned r = (v.u + 0x7FFF + ((v.u >> 16) & 1)) >> 16;  // RNE
    return (unsigned short)r;
}

__device__ inline void gload16(const void* g, void* l) {
    __builtin_amdgcn_global_load_lds(
        (const __attribute__((address_space(1))) void*)g,
        (__attribute__((address_space(3))) void*)l, 16, 0, 0);
}

// ---------------- degree / norm ----------------

__global__ void deg_kernel(const int* __restrict__ src, const int* __restrict__ dst,
                           float* __restrict__ dout, float* __restrict__ din, int E) {
    int i = blockIdx.x * blockDim.x + threadIdx.x;
    if (i < E) {
        atomicAdd(&dout[src[i]], 1.0f);
        atomicAdd(&din[dst[i]], 1.0f);
    }
}

__global__ void invsqrt_kernel(float* __restrict__ dout, float* __restrict__ din, int n) {
    int i = blockIdx.x * blockDim.x + threadIdx.x;
    if (i < n) {
        dout[i] = rsqrtf(fmaxf(dout[i], 1.0f));
        din[i]  = rsqrtf(fmaxf(din[i],  1.0f));
    }
}

// ---------------- conversions ----------------

// y[i..i+7] = bf16(x[i..i+7] * rs[i>>logK])
__global__ __launch_bounds__(256) void scale_cvt(
    const float* __restrict__ x, const float* __restrict__ rs,
    unsigned short* __restrict__ y, int logK, size_t total)
{
    size_t i = ((size_t)blockIdx.x * 256 + threadIdx.x) * 8;
    if (i >= total) return;
    float s = rs[i >> logK];
    float4 a = *reinterpret_cast<const float4*>(x + i);
    float4 b = *reinterpret_cast<const float4*>(x + i + 4);
    short8 o;
    o[0] = (short)f2bf(a.x * s); o[1] = (short)f2bf(a.y * s);
    o[2] = (short)f2bf(a.z * s); o[3] = (short)f2bf(a.w * s);
    o[4] = (short)f2bf(b.x * s); o[5] = (short)f2bf(b.y * s);
    o[6] = (short)f2bf(b.z * s); o[7] = (short)f2bf(b.w * s);
    *reinterpret_cast<short8*>(y + i) = o;
}

// Wt[n][k] = bf16(W[k][n]);  W: [K][N]
__global__ void transpose_cvt(const float* __restrict__ W, unsigned short* __restrict__ Wt,
                              int K, int N) {
    int i = blockIdx.x * 256 + threadIdx.x;
    if (i < N * K) {
        int n = i / K, k = i - n * K;
        Wt[i] = f2bf(W[(size_t)k * N + n]);
    }
}

// ---------------- bf16 MFMA GEMM: C[M,Nc] = A[M,K] @ Bt[Nc,K]^T ----------------
// 128x128 tile, BK=32, 4 waves (2x2), 16x16x32 MFMA, global_load_lds staging,
// XOR-swizzled k-quads for conflict-free ds_read_b128.

#define TM 128
#define TN 128
#define TK 32

__global__ __launch_bounds__(256) void gemm_bf16_mfma(
    const unsigned short* __restrict__ A,   // [M][K] bf16
    const unsigned short* __restrict__ Bt,  // [Nc][K] bf16
    float* __restrict__ C, int M, int K, int Nc)
{
    __shared__ unsigned short As[TM][TK];   // 8 KB
    __shared__ unsigned short Bs[TN][TK];   // 8 KB

    const int tid  = threadIdx.x;
    const int lane = tid & 63;
    const int wave = tid >> 6;
    const int wr = wave >> 1, wc = wave & 1;
    const int lrow = lane & 15;
    const int lkg  = lane >> 4;

    const int m0 = blockIdx.y * TM;
    const int n0 = blockIdx.x * TN;

    // staging: slot s (0..511) covers row=s>>2, 16B k-quad; source k-quad XOR-swizzled
    const int s0 = wave * 64 + lane;
    const int s1 = s0 + 256;
    const int r0 = s0 >> 2, q0 = (s0 & 3) ^ ((s0 >> 3) & 3);
    const int r1 = s1 >> 2, q1 = (s1 & 3) ^ ((s1 >> 3) & 3);

    char* AsB = (char*)&As[0][0];
    char* BsB = (char*)&Bs[0][0];
    void* ldsA0 = AsB + wave * 1024;            // wave-uniform bases
    void* ldsA1 = AsB + 4096 + wave * 1024;
    void* ldsB0 = BsB + wave * 1024;
    void* ldsB1 = BsB + 4096 + wave * 1024;

    // fragment read slot: kg ^ ((row>>1)&3)   (row = ...*16 + lrow, so only lrow matters)
    const int rslot = (lkg ^ ((lrow >> 1) & 3)) * 8;

    f32x4 acc[4][4] = {};

    const int nk = K / TK;
    for (int kt = 0; kt < nk; ++kt) {
        const int k0 = kt * TK;
        gload16(A  + (size_t)(m0 + r0) * K + k0 + q0 * 8, ldsA0);
        gload16(A  + (size_t)(m0 + r1) * K + k0 + q1 * 8, ldsA1);
        gload16(Bt + (size_t)(n0 + r0) * K + k0 + q0 * 8, ldsB0);
        gload16(Bt + (size_t)(n0 + r1) * K + k0 + q1 * 8, ldsB1);
        __syncthreads();   // drains vmcnt before use

        short8 af[4], bfr[4];
        #pragma unroll
        for (int mi = 0; mi < 4; ++mi)
            af[mi] = *reinterpret_cast<const short8*>(&As[wr * 64 + mi * 16 + lrow][rslot]);
        #pragma unroll
        for (int ni = 0; ni < 4; ++ni)
            bfr[ni] = *reinterpret_cast<const short8*>(&Bs[wc * 64 + ni * 16 + lrow][rslot]);

        #pragma unroll
        for (int mi = 0; mi < 4; ++mi)
            #pragma unroll
            for (int ni = 0; ni < 4; ++ni)
                acc[mi][ni] = __builtin_amdgcn_mfma_f32_16x16x32_bf16(
                    af[mi], bfr[ni], acc[mi][ni], 0, 0, 0);

        __syncthreads();   // protect LDS before next stage
    }

    #pragma unroll
    for (int mi = 0; mi < 4; ++mi)
        #pragma unroll
        for (int ni = 0; ni < 4; ++ni)
            #pragma unroll
            for (int r = 0; r < 4; ++r)
                C[(size_t)(m0 + wr * 64 + mi * 16 + lkg * 4 + r) * Nc
                  + (n0 + wc * 64 + ni * 16 + lrow)] = acc[mi][ni][r];
}

// ---------------- edge scatter-add: agg[dst] += X[src] ----------------

template<int DIM>
__global__ __launch_bounds__(256) void scatter_add(
    const int* __restrict__ src, const int* __restrict__ dst,
    const float* __restrict__ X, float* __restrict__ agg, int E)
{
    int e = blockIdx.x;
    int s = src[e], d = dst[e];
    const float* xr = X + (size_t)s * DIM;
    float* ar = agg + (size_t)d * DIM;
    #pragma unroll
    for (int j = threadIdx.x; j < DIM; j += 256)
        atomicAdd(&ar[j], xr[j]);
}

// ---------------- fused: v = elu(agg*isi + b1) * iso -> bf16 ----------------

__global__ __launch_bounds__(256) void elu_scale_bf16(
    const float* __restrict__ agg, const float* __restrict__ isi,
    const float* __restrict__ iso, const float* __restrict__ b1,
    unsigned short* __restrict__ out, size_t total)
{
    size_t i = ((size_t)blockIdx.x * 256 + threadIdx.x) * 8;
    if (i >= total) return;
    int n = (int)(i >> 9);          // / HID
    int j = (int)(i & 511);
    float si = isi[n], so = iso[n];
    float4 a = *reinterpret_cast<const float4*>(agg + i);
    float4 b = *reinterpret_cast<const float4*>(agg + i + 4);
    float4 c1 = *reinterpret_cast<const float4*>(b1 + j);
    float4 c2 = *reinterpret_cast<const float4*>(b1 + j + 4);
    float v[8] = { a.x * si + c1.x, a.y * si + c1.y, a.z * si + c1.z, a.w * si + c1.w,
                   b.x * si + c2.x, b.y * si + c2.y, b.z * si + c2.z, b.w * si + c2.w };
    short8 o;
    #pragma unroll
    for (int t = 0; t < 8; ++t) {
        float e = v[t] > 0.f ? v[t] : expm1f(v[t]);
        o[t] = (short)f2bf(e * so);
    }
    *reinterpret_cast<short8*>(out + i) = o;
}

// ---------------- finalize: out = out*isi + b2 ----------------

__global__ void finalize(float* __restrict__ out, const float* __restrict__ isi,
                         const float* __restrict__ b2, int total)
{
    int i = blockIdx.x * blockDim.x + threadIdx.x;
    if (i < total) {
        int n = i >> 8;       // / OUTD
        int j = i & 255;
        out[i] = out[i] * isi[n] + b2[j];
    }
}

// ---------------- launch ----------------

extern "C" void kernel_launch(void* const* d_in, const int* in_sizes, int n_in,
                              void* d_out, int out_size, void* d_ws, size_t ws_size,
                              hipStream_t stream) {
    const float* h  = (const float*)d_in[0];
    const float* W1 = (const float*)d_in[1];
    const float* b1 = (const float*)d_in[2];
    const float* W2 = (const float*)d_in[3];
    const float* b2 = (const float*)d_in[4];
    const int*   src = (const int*)d_in[5];
    const int*   dst = (const int*)d_in[6];

    const int N = in_sizes[0] / IN_DIM;   // 65536
    const int E = in_sizes[5];            // 524288
    float* out = (float*)d_out;

    // workspace layout
    float* iso = (float*)d_ws;                               // N
    float* isi = iso + N;                                    // N
    unsigned short* W1t = (unsigned short*)(isi + N);        // IN_DIM*HID bf16
    unsigned short* W2t = W1t + (size_t)IN_DIM * HID;        // HID*OUTD bf16
    unsigned short* hb  = W2t + (size_t)HID * OUTD;          // region R1: N*IN_DIM bf16 (134MB)
    float* R1f = (float*)hb;                                 // alias: N*HID f32 (agg1), then N*OUTD f32 (gemm2 out)
    float* R2  = (float*)(hb + (size_t)N * IN_DIM);          // region R2: N*HID f32 (gemm1 out)
    unsigned short* R2h = (unsigned short*)R2;               // alias: N*HID bf16 (x1 scaled)

    hipMemsetAsync(iso, 0, sizeof(float) * (size_t)2 * N, stream);
    hipMemsetAsync(out, 0, sizeof(float) * (size_t)N * OUTD, stream);

    deg_kernel<<<(E + 255) / 256, 256, 0, stream>>>(src, dst, iso, isi, E);
    invsqrt_kernel<<<(N + 255) / 256, 256, 0, stream>>>(iso, isi, N);

    // hb = bf16(iso ⊙ h); weights -> bf16 transposed
    scale_cvt<<<(unsigned)(((size_t)N * IN_DIM / 8 + 255) / 256), 256, 0, stream>>>(
        h, iso, hb, 10, (size_t)N * IN_DIM);
    transpose_cvt<<<(IN_DIM * HID + 255) / 256, 256, 0, stream>>>(W1, W1t, IN_DIM, HID);
    transpose_cvt<<<(HID * OUTD + 255) / 256, 256, 0, stream>>>(W2, W2t, HID, OUTD);

    // Layer 1 GEMM: R2 = hb @ W1
    dim3 g1(HID / TN, N / TM);
    gemm_bf16_mfma<<<g1, 256, 0, stream>>>(hb, W1t, R2, N, IN_DIM, HID);

    // aggregate
    hipMemsetAsync(R1f, 0, sizeof(float) * (size_t)N * HID, stream);
    scatter_add<HID><<<E, 256, 0, stream>>>(src, dst, R2, R1f, E);

    // x1s = bf16(elu(agg*isi + b1) * iso)
    elu_scale_bf16<<<(unsigned)(((size_t)N * HID / 8 + 255) / 256), 256, 0, stream>>>(
        R1f, isi, iso, b1, R2h, (size_t)N * HID);

    // Layer 2 GEMM: R1f = x1s @ W2
    dim3 g2(OUTD / TN, N / TM);
    gemm_bf16_mfma<<<g2, 256, 0, stream>>>(R2h, W2t, R1f, N, HID, OUTD);

    // aggregate + finalize
    scatter_add<OUTD><<<E, 256, 0, stream>>>(src, dst, R1f, out, E);
    finalize<<<(N * OUTD + 255) / 256, 256, 0, stream>>>(out, isi, b2, N * OUTD);
}

// Round 3
// 544.876 us; speedup vs baseline: 5.0698x; 3.0466x over previous
//
#include <hip/hip_runtime.h>
#include <hip/hip_bf16.h>

#define IN_DIM 1024
#define HID 512
#define OUTD 256

typedef __attribute__((ext_vector_type(8))) short short8;
typedef __attribute__((ext_vector_type(4))) float f32x4;

// ---------------- helpers ----------------

__device__ inline unsigned short f2bf(float f) {
    union { float f; unsigned u; } v; v.f = f;
    unsigned r = (v.u + 0x7FFF + ((v.u >> 16) & 1)) >> 16;  // RNE
    return (unsigned short)r;
}

__device__ inline void gload16(const void* g, void* l) {
    __builtin_amdgcn_global_load_lds(
        (const __attribute__((address_space(1))) void*)g,
        (__attribute__((address_space(3))) void*)l, 16, 0, 0);
}

// ---------------- degree / norm ----------------

__global__ void deg_kernel(const int* __restrict__ src, const int* __restrict__ dst,
                           int* __restrict__ dego, int* __restrict__ degi, int E) {
    int i = blockIdx.x * blockDim.x + threadIdx.x;
    if (i < E) {
        atomicAdd(&dego[src[i]], 1);
        atomicAdd(&degi[dst[i]], 1);
    }
}

__global__ void invsqrt_kernel(const int* __restrict__ dego, const int* __restrict__ degi,
                               float* __restrict__ iso, float* __restrict__ isi, int n) {
    int i = blockIdx.x * blockDim.x + threadIdx.x;
    if (i < n) {
        iso[i] = rsqrtf(fmaxf((float)dego[i], 1.0f));
        isi[i] = rsqrtf(fmaxf((float)degi[i], 1.0f));
    }
}

// ---------------- exclusive scan over N=65536 (256 blocks x 256) ----------------

__global__ __launch_bounds__(256) void scan_block(const int* __restrict__ deg,
                                                  int* __restrict__ excl,
                                                  int* __restrict__ partials) {
    __shared__ int tmp[256];
    int tid = threadIdx.x;
    int i = blockIdx.x * 256 + tid;
    int v = deg[i];
    tmp[tid] = v;
    __syncthreads();
    #pragma unroll
    for (int off = 1; off < 256; off <<= 1) {
        int t = (tid >= off) ? tmp[tid - off] : 0;
        __syncthreads();
        tmp[tid] += t;
        __syncthreads();
    }
    excl[i] = tmp[tid] - v;
    if (tid == 255) partials[blockIdx.x] = tmp[255];
}

__global__ __launch_bounds__(256) void scan_partials(int* __restrict__ partials) {
    __shared__ int tmp[256];
    int tid = threadIdx.x;
    int v = partials[tid];
    tmp[tid] = v;
    __syncthreads();
    #pragma unroll
    for (int off = 1; off < 256; off <<= 1) {
        int t = (tid >= off) ? tmp[tid - off] : 0;
        __syncthreads();
        tmp[tid] += t;
        __syncthreads();
    }
    partials[tid] = tmp[tid] - v;   // exclusive
}

__global__ __launch_bounds__(256) void scan_add(const int* __restrict__ excl,
                                                const int* __restrict__ partials,
                                                const int* __restrict__ deg,
                                                int* __restrict__ row_start,
                                                int* __restrict__ cursor, int n) {
    int i = blockIdx.x * 256 + threadIdx.x;
    int v = excl[i] + partials[blockIdx.x];
    row_start[i] = v;
    cursor[i] = v;
    if (i == n - 1) row_start[n] = v + deg[i];
}

__global__ void csr_fill(const int* __restrict__ src, const int* __restrict__ dst,
                         int* __restrict__ cursor, int* __restrict__ eidx, int E) {
    int e = blockIdx.x * blockDim.x + threadIdx.x;
    if (e < E) {
        int pos = atomicAdd(&cursor[dst[e]], 1);
        eidx[pos] = src[e];
    }
}

// ---------------- conversions ----------------

__global__ __launch_bounds__(256) void scale_cvt(
    const float* __restrict__ x, const float* __restrict__ rs,
    unsigned short* __restrict__ y, int logK, size_t total)
{
    size_t i = ((size_t)blockIdx.x * 256 + threadIdx.x) * 8;
    if (i >= total) return;
    float s = rs[i >> logK];
    float4 a = *reinterpret_cast<const float4*>(x + i);
    float4 b = *reinterpret_cast<const float4*>(x + i + 4);
    short8 o;
    o[0] = (short)f2bf(a.x * s); o[1] = (short)f2bf(a.y * s);
    o[2] = (short)f2bf(a.z * s); o[3] = (short)f2bf(a.w * s);
    o[4] = (short)f2bf(b.x * s); o[5] = (short)f2bf(b.y * s);
    o[6] = (short)f2bf(b.z * s); o[7] = (short)f2bf(b.w * s);
    *reinterpret_cast<short8*>(y + i) = o;
}

__global__ void transpose_cvt(const float* __restrict__ W, unsigned short* __restrict__ Wt,
                              int K, int N) {
    int i = blockIdx.x * 256 + threadIdx.x;
    if (i < N * K) {
        int n = i / K, k = i - n * K;
        Wt[i] = f2bf(W[(size_t)k * N + n]);
    }
}

// ---------------- bf16 MFMA GEMM (unchanged from round 2) ----------------

#define TM 128
#define TN 128
#define TK 32

__global__ __launch_bounds__(256) void gemm_bf16_mfma(
    const unsigned short* __restrict__ A,   // [M][K] bf16
    const unsigned short* __restrict__ Bt,  // [Nc][K] bf16
    float* __restrict__ C, int M, int K, int Nc)
{
    __shared__ unsigned short As[TM][TK];
    __shared__ unsigned short Bs[TN][TK];

    const int tid  = threadIdx.x;
    const int lane = tid & 63;
    const int wave = tid >> 6;
    const int wr = wave >> 1, wc = wave & 1;
    const int lrow = lane & 15;
    const int lkg  = lane >> 4;

    const int m0 = blockIdx.y * TM;
    const int n0 = blockIdx.x * TN;

    const int s0 = wave * 64 + lane;
    const int s1 = s0 + 256;
    const int r0 = s0 >> 2, q0 = (s0 & 3) ^ ((s0 >> 3) & 3);
    const int r1 = s1 >> 2, q1 = (s1 & 3) ^ ((s1 >> 3) & 3);

    char* AsB = (char*)&As[0][0];
    char* BsB = (char*)&Bs[0][0];
    void* ldsA0 = AsB + wave * 1024;
    void* ldsA1 = AsB + 4096 + wave * 1024;
    void* ldsB0 = BsB + wave * 1024;
    void* ldsB1 = BsB + 4096 + wave * 1024;

    const int rslot = (lkg ^ ((lrow >> 1) & 3)) * 8;

    f32x4 acc[4][4] = {};

    const int nk = K / TK;
    for (int kt = 0; kt < nk; ++kt) {
        const int k0 = kt * TK;
        gload16(A  + (size_t)(m0 + r0) * K + k0 + q0 * 8, ldsA0);
        gload16(A  + (size_t)(m0 + r1) * K + k0 + q1 * 8, ldsA1);
        gload16(Bt + (size_t)(n0 + r0) * K + k0 + q0 * 8, ldsB0);
        gload16(Bt + (size_t)(n0 + r1) * K + k0 + q1 * 8, ldsB1);
        __syncthreads();

        short8 af[4], bfr[4];
        #pragma unroll
        for (int mi = 0; mi < 4; ++mi)
            af[mi] = *reinterpret_cast<const short8*>(&As[wr * 64 + mi * 16 + lrow][rslot]);
        #pragma unroll
        for (int ni = 0; ni < 4; ++ni)
            bfr[ni] = *reinterpret_cast<const short8*>(&Bs[wc * 64 + ni * 16 + lrow][rslot]);

        #pragma unroll
        for (int mi = 0; mi < 4; ++mi)
            #pragma unroll
            for (int ni = 0; ni < 4; ++ni)
                acc[mi][ni] = __builtin_amdgcn_mfma_f32_16x16x32_bf16(
                    af[mi], bfr[ni], acc[mi][ni], 0, 0, 0);

        __syncthreads();
    }

    #pragma unroll
    for (int mi = 0; mi < 4; ++mi)
        #pragma unroll
        for (int ni = 0; ni < 4; ++ni)
            #pragma unroll
            for (int r = 0; r < 4; ++r)
                C[(size_t)(m0 + wr * 64 + mi * 16 + lkg * 4 + r) * Nc
                  + (n0 + wc * 64 + ni * 16 + lrow)] = acc[mi][ni][r];
}

// ---------------- CSR gather-aggregate, fused epilogues ----------------
// One wave per node; lane owns DIM/64 contiguous floats.
// LAYER1: out_bf = bf16(elu(sum*isi + bias) * iso)
// else:   out_f  = sum*isi + bias

template<int DIM, bool LAYER1>
__global__ __launch_bounds__(256) void aggregate(
    const int* __restrict__ row_start, const int* __restrict__ eidx,
    const float* __restrict__ X, const float* __restrict__ isi,
    const float* __restrict__ iso, const float* __restrict__ bias,
    unsigned short* __restrict__ out_bf, float* __restrict__ out_f)
{
    constexpr int F = DIM / 64;           // 8 (HID) or 4 (OUTD)
    const int node = blockIdx.x * 4 + (threadIdx.x >> 6);
    const int lane = threadIdx.x & 63;

    const int beg = row_start[node];
    const int end = row_start[node + 1];

    float acc[F] = {};
    for (int e = beg; e < end; ++e) {
        const float* xr = X + (size_t)eidx[e] * DIM + lane * F;
        #pragma unroll
        for (int q = 0; q < F / 4; ++q) {
            float4 v = *reinterpret_cast<const float4*>(xr + q * 4);
            acc[q * 4 + 0] += v.x; acc[q * 4 + 1] += v.y;
            acc[q * 4 + 2] += v.z; acc[q * 4 + 3] += v.w;
        }
    }

    const float si = isi[node];
    float bv[F];
    #pragma unroll
    for (int q = 0; q < F / 4; ++q)
        *reinterpret_cast<float4*>(&bv[q * 4]) =
            *reinterpret_cast<const float4*>(bias + lane * F + q * 4);

    if (LAYER1) {
        const float so = iso[node];
        short8 o;
        #pragma unroll
        for (int f = 0; f < F; ++f) {
            float v = acc[f] * si + bv[f];
            v = v > 0.f ? v : expm1f(v);
            o[f] = (short)f2bf(v * so);
        }
        *reinterpret_cast<short8*>(out_bf + (size_t)node * DIM + lane * F) = o;
    } else {
        #pragma unroll
        for (int q = 0; q < F / 4; ++q) {
            float4 v = make_float4(acc[q * 4 + 0] * si + bv[q * 4 + 0],
                                   acc[q * 4 + 1] * si + bv[q * 4 + 1],
                                   acc[q * 4 + 2] * si + bv[q * 4 + 2],
                                   acc[q * 4 + 3] * si + bv[q * 4 + 3]);
            *reinterpret_cast<float4*>(out_f + (size_t)node * DIM + lane * F + q * 4) = v;
        }
    }
}

// ---------------- launch ----------------

extern "C" void kernel_launch(void* const* d_in, const int* in_sizes, int n_in,
                              void* d_out, int out_size, void* d_ws, size_t ws_size,
                              hipStream_t stream) {
    const float* h  = (const float*)d_in[0];
    const float* W1 = (const float*)d_in[1];
    const float* b1 = (const float*)d_in[2];
    const float* W2 = (const float*)d_in[3];
    const float* b2 = (const float*)d_in[4];
    const int*   src = (const int*)d_in[5];
    const int*   dst = (const int*)d_in[6];

    const int N = in_sizes[0] / IN_DIM;   // 65536
    const int E = in_sizes[5];            // 524288
    float* out = (float*)d_out;

    // ---- workspace layout ----
    int* dego      = (int*)d_ws;                   // N
    int* degi      = dego + N;                     // N
    int* excl      = degi + N;                     // N
    int* partials  = excl + N;                     // 256
    int* row_start = partials + 256;               // N+1 (pad to N+64)
    int* cursor    = row_start + N + 64;           // N
    int* eidx      = cursor + N;                   // E
    float* iso     = (float*)(eidx + E);           // N
    float* isi     = iso + N;                      // N
    unsigned short* W1t = (unsigned short*)(isi + N);      // IN_DIM*HID
    unsigned short* W2t = W1t + (size_t)IN_DIM * HID;      // HID*OUTD
    unsigned short* hb  = W2t + (size_t)HID * OUTD;        // N*IN_DIM bf16 (134MB)
    unsigned short* R2h = hb;                               // alias: N*HID bf16 (after gemm1)
    float* X1 = (float*)(hb + (size_t)N * IN_DIM);          // N*HID f32 (134MB)
    float* X2 = X1;                                         // alias: N*OUTD f32 (after agg1)

    hipMemsetAsync(dego, 0, sizeof(int) * (size_t)2 * N, stream);

    deg_kernel<<<(E + 255) / 256, 256, 0, stream>>>(src, dst, dego, degi, E);
    invsqrt_kernel<<<(N + 255) / 256, 256, 0, stream>>>(dego, degi, iso, isi, N);

    // CSR by dst
    scan_block<<<N / 256, 256, 0, stream>>>(degi, excl, partials);
    scan_partials<<<1, 256, 0, stream>>>(partials);
    scan_add<<<N / 256, 256, 0, stream>>>(excl, partials, degi, row_start, cursor, N);
    csr_fill<<<(E + 255) / 256, 256, 0, stream>>>(src, dst, cursor, eidx, E);

    // hb = bf16(iso ⊙ h); weights -> bf16 transposed
    scale_cvt<<<(unsigned)(((size_t)N * IN_DIM / 8 + 255) / 256), 256, 0, stream>>>(
        h, iso, hb, 10, (size_t)N * IN_DIM);
    transpose_cvt<<<(IN_DIM * HID + 255) / 256, 256, 0, stream>>>(W1, W1t, IN_DIM, HID);
    transpose_cvt<<<(HID * OUTD + 255) / 256, 256, 0, stream>>>(W2, W2t, HID, OUTD);

    // Layer 1: X1 = hb @ W1 ; R2h = bf16(elu(agg(X1)*isi + b1) * iso)
    dim3 g1(HID / TN, N / TM);
    gemm_bf16_mfma<<<g1, 256, 0, stream>>>(hb, W1t, X1, N, IN_DIM, HID);
    aggregate<HID, true><<<N / 4, 256, 0, stream>>>(
        row_start, eidx, X1, isi, iso, b1, R2h, nullptr);

    // Layer 2: X2 = R2h @ W2 ; out = agg(X2)*isi + b2
    dim3 g2(OUTD / TN, N / TM);
    gemm_bf16_mfma<<<g2, 256, 0, stream>>>(R2h, W2t, X2, N, HID, OUTD);
    aggregate<OUTD, false><<<N / 4, 256, 0, stream>>>(
        row_start, eidx, X2, isi, iso, b2, nullptr, out);
}

// Round 4
// 438.469 us; speedup vs baseline: 6.3001x; 1.2427x over previous
//
#include <hip/hip_runtime.h>
#include <hip/hip_bf16.h>

#define IN_DIM 1024
#define HID 512
#define OUTD 256

typedef __attribute__((ext_vector_type(8))) short short8;
typedef __attribute__((ext_vector_type(4))) float f32x4;
typedef __attribute__((ext_vector_type(8))) unsigned short ushort8e;
typedef __attribute__((ext_vector_type(4))) unsigned short ushort4e;

template<int F> struct VecSel;
template<> struct VecSel<8> { using T = ushort8e; };
template<> struct VecSel<4> { using T = ushort4e; };

// ---------------- helpers ----------------

__device__ inline unsigned short f2bf(float f) {
    union { float f; unsigned u; } v; v.f = f;
    unsigned r = (v.u + 0x7FFF + ((v.u >> 16) & 1)) >> 16;  // RNE
    return (unsigned short)r;
}

__device__ inline float bf2f(unsigned short u) {
    union { unsigned u; float f; } v; v.u = ((unsigned)u) << 16; return v.f;
}

__device__ inline void gload16(const void* g, void* l) {
    __builtin_amdgcn_global_load_lds(
        (const __attribute__((address_space(1))) void*)g,
        (__attribute__((address_space(3))) void*)l, 16, 0, 0);
}

// ---------------- degree / norm ----------------

__global__ void deg_kernel(const int* __restrict__ src, const int* __restrict__ dst,
                           int* __restrict__ dego, int* __restrict__ degi, int E) {
    int i = blockIdx.x * blockDim.x + threadIdx.x;
    if (i < E) {
        atomicAdd(&dego[src[i]], 1);
        atomicAdd(&degi[dst[i]], 1);
    }
}

__global__ void invsqrt_kernel(const int* __restrict__ dego, const int* __restrict__ degi,
                               float* __restrict__ iso, float* __restrict__ isi, int n) {
    int i = blockIdx.x * blockDim.x + threadIdx.x;
    if (i < n) {
        iso[i] = rsqrtf(fmaxf((float)dego[i], 1.0f));
        isi[i] = rsqrtf(fmaxf((float)degi[i], 1.0f));
    }
}

// ---------------- exclusive scan over N=65536 (256 blocks x 256) ----------------

__global__ __launch_bounds__(256) void scan_block(const int* __restrict__ deg,
                                                  int* __restrict__ excl,
                                                  int* __restrict__ partials) {
    __shared__ int tmp[256];
    int tid = threadIdx.x;
    int i = blockIdx.x * 256 + tid;
    int v = deg[i];
    tmp[tid] = v;
    __syncthreads();
    #pragma unroll
    for (int off = 1; off < 256; off <<= 1) {
        int t = (tid >= off) ? tmp[tid - off] : 0;
        __syncthreads();
        tmp[tid] += t;
        __syncthreads();
    }
    excl[i] = tmp[tid] - v;
    if (tid == 255) partials[blockIdx.x] = tmp[255];
}

__global__ __launch_bounds__(256) void scan_partials(int* __restrict__ partials) {
    __shared__ int tmp[256];
    int tid = threadIdx.x;
    int v = partials[tid];
    tmp[tid] = v;
    __syncthreads();
    #pragma unroll
    for (int off = 1; off < 256; off <<= 1) {
        int t = (tid >= off) ? tmp[tid - off] : 0;
        __syncthreads();
        tmp[tid] += t;
        __syncthreads();
    }
    partials[tid] = tmp[tid] - v;   // exclusive
}

__global__ __launch_bounds__(256) void scan_add(const int* __restrict__ excl,
                                                const int* __restrict__ partials,
                                                const int* __restrict__ deg,
                                                int* __restrict__ row_start,
                                                int* __restrict__ cursor, int n) {
    int i = blockIdx.x * 256 + threadIdx.x;
    int v = excl[i] + partials[blockIdx.x];
    row_start[i] = v;
    cursor[i] = v;
    if (i == n - 1) row_start[n] = v + deg[i];
}

__global__ void csr_fill(const int* __restrict__ src, const int* __restrict__ dst,
                         int* __restrict__ cursor, int* __restrict__ eidx, int E) {
    int e = blockIdx.x * blockDim.x + threadIdx.x;
    if (e < E) {
        int pos = atomicAdd(&cursor[dst[e]], 1);
        eidx[pos] = src[e];
    }
}

// ---------------- conversions ----------------

__global__ __launch_bounds__(256) void scale_cvt(
    const float* __restrict__ x, const float* __restrict__ rs,
    unsigned short* __restrict__ y, int logK, size_t total)
{
    size_t i = ((size_t)blockIdx.x * 256 + threadIdx.x) * 8;
    if (i >= total) return;
    float s = rs[i >> logK];
    float4 a = *reinterpret_cast<const float4*>(x + i);
    float4 b = *reinterpret_cast<const float4*>(x + i + 4);
    short8 o;
    o[0] = (short)f2bf(a.x * s); o[1] = (short)f2bf(a.y * s);
    o[2] = (short)f2bf(a.z * s); o[3] = (short)f2bf(a.w * s);
    o[4] = (short)f2bf(b.x * s); o[5] = (short)f2bf(b.y * s);
    o[6] = (short)f2bf(b.z * s); o[7] = (short)f2bf(b.w * s);
    *reinterpret_cast<short8*>(y + i) = o;
}

__global__ void transpose_cvt(const float* __restrict__ W, unsigned short* __restrict__ Wt,
                              int K, int N) {
    int i = blockIdx.x * 256 + threadIdx.x;
    if (i < N * K) {
        int n = i / K, k = i - n * K;
        Wt[i] = f2bf(W[(size_t)k * N + n]);
    }
}

// ---------------- bf16 MFMA GEMM: C = A[M,K] @ Bt[Nc,K]^T, bf16 output ----------------

#define TM 128
#define TN 128
#define TK 32

__global__ __launch_bounds__(256) void gemm_bf16_mfma(
    const unsigned short* __restrict__ A,   // [M][K] bf16
    const unsigned short* __restrict__ Bt,  // [Nc][K] bf16
    unsigned short* __restrict__ Cb,        // [M][Nc] bf16
    int M, int K, int Nc)
{
    __shared__ unsigned short As[TM][TK];
    __shared__ unsigned short Bs[TN][TK];

    const int tid  = threadIdx.x;
    const int lane = tid & 63;
    const int wave = tid >> 6;
    const int wr = wave >> 1, wc = wave & 1;
    const int lrow = lane & 15;
    const int lkg  = lane >> 4;

    const int m0 = blockIdx.y * TM;
    const int n0 = blockIdx.x * TN;

    const int s0 = wave * 64 + lane;
    const int s1 = s0 + 256;
    const int r0 = s0 >> 2, q0 = (s0 & 3) ^ ((s0 >> 3) & 3);
    const int r1 = s1 >> 2, q1 = (s1 & 3) ^ ((s1 >> 3) & 3);

    char* AsB = (char*)&As[0][0];
    char* BsB = (char*)&Bs[0][0];
    void* ldsA0 = AsB + wave * 1024;
    void* ldsA1 = AsB + 4096 + wave * 1024;
    void* ldsB0 = BsB + wave * 1024;
    void* ldsB1 = BsB + 4096 + wave * 1024;

    const int rslot = (lkg ^ ((lrow >> 1) & 3)) * 8;

    f32x4 acc[4][4] = {};

    const int nk = K / TK;
    for (int kt = 0; kt < nk; ++kt) {
        const int k0 = kt * TK;
        gload16(A  + (size_t)(m0 + r0) * K + k0 + q0 * 8, ldsA0);
        gload16(A  + (size_t)(m0 + r1) * K + k0 + q1 * 8, ldsA1);
        gload16(Bt + (size_t)(n0 + r0) * K + k0 + q0 * 8, ldsB0);
        gload16(Bt + (size_t)(n0 + r1) * K + k0 + q1 * 8, ldsB1);
        __syncthreads();

        short8 af[4], bfr[4];
        #pragma unroll
        for (int mi = 0; mi < 4; ++mi)
            af[mi] = *reinterpret_cast<const short8*>(&As[wr * 64 + mi * 16 + lrow][rslot]);
        #pragma unroll
        for (int ni = 0; ni < 4; ++ni)
            bfr[ni] = *reinterpret_cast<const short8*>(&Bs[wc * 64 + ni * 16 + lrow][rslot]);

        #pragma unroll
        for (int mi = 0; mi < 4; ++mi)
            #pragma unroll
            for (int ni = 0; ni < 4; ++ni)
                acc[mi][ni] = __builtin_amdgcn_mfma_f32_16x16x32_bf16(
                    af[mi], bfr[ni], acc[mi][ni], 0, 0, 0);

        __syncthreads();
    }

    #pragma unroll
    for (int mi = 0; mi < 4; ++mi)
        #pragma unroll
        for (int ni = 0; ni < 4; ++ni)
            #pragma unroll
            for (int r = 0; r < 4; ++r)
                Cb[(size_t)(m0 + wr * 64 + mi * 16 + lkg * 4 + r) * Nc
                   + (n0 + wc * 64 + ni * 16 + lrow)] = f2bf(acc[mi][ni][r]);
}

// ---------------- CSR gather-aggregate (bf16 X), fused epilogues ----------------
// One wave per node; lane owns DIM/64 contiguous elems.
// LAYER1: out_bf = bf16(elu(sum*isi + bias) * iso)
// else:   out_f  = sum*isi + bias

template<int DIM, bool LAYER1>
__global__ __launch_bounds__(256) void aggregate(
    const int* __restrict__ row_start, const int* __restrict__ eidx,
    const unsigned short* __restrict__ Xb, const float* __restrict__ isi,
    const float* __restrict__ iso, const float* __restrict__ bias,
    unsigned short* __restrict__ out_bf, float* __restrict__ out_f)
{
    constexpr int F = DIM / 64;           // 8 (HID) or 4 (OUTD)
    using VecT = typename VecSel<F>::T;
    const int node = blockIdx.x * 4 + (threadIdx.x >> 6);
    const int lane = threadIdx.x & 63;

    const int beg = row_start[node];
    const int end = row_start[node + 1];
    const unsigned short* base = Xb + lane * F;

    float acc[F] = {};
    int e = beg;
    for (; e + 1 < end; e += 2) {
        int i0 = eidx[e], i1 = eidx[e + 1];
        VecT v0 = *reinterpret_cast<const VecT*>(base + (size_t)i0 * DIM);
        VecT v1 = *reinterpret_cast<const VecT*>(base + (size_t)i1 * DIM);
        #pragma unroll
        for (int f = 0; f < F; ++f) { acc[f] += bf2f(v0[f]); acc[f] += bf2f(v1[f]); }
    }
    if (e < end) {
        VecT v0 = *reinterpret_cast<const VecT*>(base + (size_t)eidx[e] * DIM);
        #pragma unroll
        for (int f = 0; f < F; ++f) acc[f] += bf2f(v0[f]);
    }

    const float si = isi[node];
    float bv[F];
    #pragma unroll
    for (int q = 0; q < F / 4; ++q)
        *reinterpret_cast<float4*>(&bv[q * 4]) =
            *reinterpret_cast<const float4*>(bias + lane * F + q * 4);

    if (LAYER1) {
        const float so = iso[node];
        short8 o;
        #pragma unroll
        for (int f = 0; f < F; ++f) {
            float v = acc[f] * si + bv[f];
            v = v > 0.f ? v : expm1f(v);
            o[f] = (short)f2bf(v * so);
        }
        *reinterpret_cast<short8*>(out_bf + (size_t)node * DIM + lane * F) = o;
    } else {
        #pragma unroll
        for (int q = 0; q < F / 4; ++q) {
            float4 v = make_float4(acc[q * 4 + 0] * si + bv[q * 4 + 0],
                                   acc[q * 4 + 1] * si + bv[q * 4 + 1],
                                   acc[q * 4 + 2] * si + bv[q * 4 + 2],
                                   acc[q * 4 + 3] * si + bv[q * 4 + 3]);
            *reinterpret_cast<float4*>(out_f + (size_t)node * DIM + lane * F + q * 4) = v;
        }
    }
}

// ---------------- launch ----------------

extern "C" void kernel_launch(void* const* d_in, const int* in_sizes, int n_in,
                              void* d_out, int out_size, void* d_ws, size_t ws_size,
                              hipStream_t stream) {
    const float* h  = (const float*)d_in[0];
    const float* W1 = (const float*)d_in[1];
    const float* b1 = (const float*)d_in[2];
    const float* W2 = (const float*)d_in[3];
    const float* b2 = (const float*)d_in[4];
    const int*   src = (const int*)d_in[5];
    const int*   dst = (const int*)d_in[6];

    const int N = in_sizes[0] / IN_DIM;   // 65536
    const int E = in_sizes[5];            // 524288
    float* out = (float*)d_out;

    // ---- workspace layout ----
    int* dego      = (int*)d_ws;                   // N
    int* degi      = dego + N;                     // N
    int* excl      = degi + N;                     // N
    int* partials  = excl + N;                     // 256
    int* row_start = partials + 256;               // N+1 (pad to N+64)
    int* cursor    = row_start + N + 64;           // N
    int* eidx      = cursor + N;                   // E
    float* iso     = (float*)(eidx + E);           // N
    float* isi     = iso + N;                      // N
    unsigned short* W1t = (unsigned short*)(isi + N);      // IN_DIM*HID
    unsigned short* W2t = W1t + (size_t)IN_DIM * HID;      // HID*OUTD
    unsigned short* hb  = W2t + (size_t)HID * OUTD;        // N*IN_DIM bf16 (134MB)
    unsigned short* X1b = hb + (size_t)N * IN_DIM;         // N*HID bf16 (67MB)
    unsigned short* X2b = X1b;                             // alias (X1 dead before gemm2 write)
    unsigned short* R2h = X1b + (size_t)N * HID;           // N*HID bf16 (67MB) — x1s

    hipMemsetAsync(dego, 0, sizeof(int) * (size_t)2 * N, stream);

    deg_kernel<<<(E + 255) / 256, 256, 0, stream>>>(src, dst, dego, degi, E);
    invsqrt_kernel<<<(N + 255) / 256, 256, 0, stream>>>(dego, degi, iso, isi, N);

    // CSR by dst
    scan_block<<<N / 256, 256, 0, stream>>>(degi, excl, partials);
    scan_partials<<<1, 256, 0, stream>>>(partials);
    scan_add<<<N / 256, 256, 0, stream>>>(excl, partials, degi, row_start, cursor, N);
    csr_fill<<<(E + 255) / 256, 256, 0, stream>>>(src, dst, cursor, eidx, E);

    // hb = bf16(iso ⊙ h); weights -> bf16 transposed
    scale_cvt<<<(unsigned)(((size_t)N * IN_DIM / 8 + 255) / 256), 256, 0, stream>>>(
        h, iso, hb, 10, (size_t)N * IN_DIM);
    transpose_cvt<<<(IN_DIM * HID + 255) / 256, 256, 0, stream>>>(W1, W1t, IN_DIM, HID);
    transpose_cvt<<<(HID * OUTD + 255) / 256, 256, 0, stream>>>(W2, W2t, HID, OUTD);

    // Layer 1: X1b = bf16(hb @ W1) ; R2h = bf16(elu(agg(X1b)*isi + b1) * iso)
    dim3 g1(HID / TN, N / TM);
    gemm_bf16_mfma<<<g1, 256, 0, stream>>>(hb, W1t, X1b, N, IN_DIM, HID);
    aggregate<HID, true><<<N / 4, 256, 0, stream>>>(
        row_start, eidx, X1b, isi, iso, b1, R2h, nullptr);

    // Layer 2: X2b = bf16(R2h @ W2) ; out = agg(X2b)*isi + b2
    dim3 g2(OUTD / TN, N / TM);
    gemm_bf16_mfma<<<g2, 256, 0, stream>>>(R2h, W2t, X2b, N, HID, OUTD);
    aggregate<OUTD, false><<<N / 4, 256, 0, stream>>>(
        row_start, eidx, X2b, isi, iso, b2, nullptr, out);
}

// Round 5
// 422.504 us; speedup vs baseline: 6.5382x; 1.0378x over previous
//
#include <hip/hip_runtime.h>
#include <hip/hip_bf16.h>

#define IN_DIM 1024
#define HID 512
#define OUTD 256

typedef __attribute__((ext_vector_type(8))) short short8;
typedef __attribute__((ext_vector_type(4))) float f32x4;
typedef __attribute__((ext_vector_type(8))) unsigned short ushort8e;
typedef __attribute__((ext_vector_type(4))) unsigned short ushort4e;

template<int F> struct VecSel;
template<> struct VecSel<8> { using T = ushort8e; };
template<> struct VecSel<4> { using T = ushort4e; };

// ---------------- helpers ----------------

__device__ inline unsigned short f2bf(float f) {
    union { float f; unsigned u; } v; v.f = f;
    unsigned r = (v.u + 0x7FFF + ((v.u >> 16) & 1)) >> 16;  // RNE
    return (unsigned short)r;
}

__device__ inline float bf2f(unsigned short u) {
    union { unsigned u; float f; } v; v.u = ((unsigned)u) << 16; return v.f;
}

__device__ inline void gload16(const void* g, void* l) {
    __builtin_amdgcn_global_load_lds(
        (const __attribute__((address_space(1))) void*)g,
        (__attribute__((address_space(3))) void*)l, 16, 0, 0);
}

// ---------------- degree / norm ----------------

__global__ void deg_kernel(const int* __restrict__ src, const int* __restrict__ dst,
                           int* __restrict__ dego, int* __restrict__ degi, int E) {
    int i = blockIdx.x * blockDim.x + threadIdx.x;
    if (i < E) {
        atomicAdd(&dego[src[i]], 1);
        atomicAdd(&degi[dst[i]], 1);
    }
}

__global__ void invsqrt_kernel(const int* __restrict__ dego, const int* __restrict__ degi,
                               float* __restrict__ iso, float* __restrict__ isi, int n) {
    int i = blockIdx.x * blockDim.x + threadIdx.x;
    if (i < n) {
        iso[i] = rsqrtf(fmaxf((float)dego[i], 1.0f));
        isi[i] = rsqrtf(fmaxf((float)degi[i], 1.0f));
    }
}

// ---------------- exclusive scan over N=65536 (256 blocks x 256) ----------------

__global__ __launch_bounds__(256) void scan_block(const int* __restrict__ deg,
                                                  int* __restrict__ excl,
                                                  int* __restrict__ partials) {
    __shared__ int tmp[256];
    int tid = threadIdx.x;
    int i = blockIdx.x * 256 + tid;
    int v = deg[i];
    tmp[tid] = v;
    __syncthreads();
    #pragma unroll
    for (int off = 1; off < 256; off <<= 1) {
        int t = (tid >= off) ? tmp[tid - off] : 0;
        __syncthreads();
        tmp[tid] += t;
        __syncthreads();
    }
    excl[i] = tmp[tid] - v;
    if (tid == 255) partials[blockIdx.x] = tmp[255];
}

__global__ __launch_bounds__(256) void scan_partials(int* __restrict__ partials) {
    __shared__ int tmp[256];
    int tid = threadIdx.x;
    int v = partials[tid];
    tmp[tid] = v;
    __syncthreads();
    #pragma unroll
    for (int off = 1; off < 256; off <<= 1) {
        int t = (tid >= off) ? tmp[tid - off] : 0;
        __syncthreads();
        tmp[tid] += t;
        __syncthreads();
    }
    partials[tid] = tmp[tid] - v;   // exclusive
}

__global__ __launch_bounds__(256) void scan_add(const int* __restrict__ excl,
                                                const int* __restrict__ partials,
                                                const int* __restrict__ deg,
                                                int* __restrict__ row_start,
                                                int* __restrict__ cursor, int n) {
    int i = blockIdx.x * 256 + threadIdx.x;
    int v = excl[i] + partials[blockIdx.x];
    row_start[i] = v;
    cursor[i] = v;
    if (i == n - 1) row_start[n] = v + deg[i];
}

__global__ void csr_fill(const int* __restrict__ src, const int* __restrict__ dst,
                         int* __restrict__ cursor, int* __restrict__ eidx, int E) {
    int e = blockIdx.x * blockDim.x + threadIdx.x;
    if (e < E) {
        int pos = atomicAdd(&cursor[dst[e]], 1);
        eidx[pos] = src[e];
    }
}

// ---------------- weight transpose+cvt ----------------

__global__ void transpose_cvt(const float* __restrict__ W, unsigned short* __restrict__ Wt,
                              int K, int N) {
    int i = blockIdx.x * 256 + threadIdx.x;
    if (i < N * K) {
        int n = i / K, k = i - n * K;
        Wt[i] = f2bf(W[(size_t)k * N + n]);
    }
}

// ---------------- bf16 MFMA GEMM: C = A[M,K] @ Bt[Nc,K]^T, bf16 output ----------------
// AF32=1: A is f32, scaled by rowscale[row] and converted to bf16 during
//         reg-staging (ds_write_b128 into the same XOR-swizzled layout).
// AF32=0: A is bf16, staged via global_load_lds (wave-uniform dest).

#define TM 128
#define TN 128
#define TK 32

template<int AF32>
__global__ __launch_bounds__(256) void gemm_bf16_mfma(
    const void* __restrict__ Ap, const unsigned short* __restrict__ Bt,
    const float* __restrict__ rowscale, unsigned short* __restrict__ Cb,
    int M, int K, int Nc)
{
    __shared__ unsigned short As[TM][TK];
    __shared__ unsigned short Bs[TN][TK];

    const int tid  = threadIdx.x;
    const int lane = tid & 63;
    const int wave = tid >> 6;
    const int wr = wave >> 1, wc = wave & 1;
    const int lrow = lane & 15;
    const int lkg  = lane >> 4;

    const int m0 = blockIdx.y * TM;
    const int n0 = blockIdx.x * TN;

    // B staging slots (and A slots for AF32=0): slot s -> row s>>2, quad (s&3)^((row>>1)&3)
    const int s0 = wave * 64 + lane;
    const int s1 = s0 + 256;
    const int r0 = s0 >> 2, q0 = (s0 & 3) ^ ((s0 >> 3) & 3);
    const int r1 = s1 >> 2, q1 = (s1 & 3) ^ ((s1 >> 3) & 3);

    char* AsB = (char*)&As[0][0];
    char* BsB = (char*)&Bs[0][0];
    void* ldsA0 = AsB + wave * 1024;
    void* ldsA1 = AsB + 4096 + wave * 1024;
    void* ldsB0 = BsB + wave * 1024;
    void* ldsB1 = BsB + 4096 + wave * 1024;

    // AF32 reg-staging: thread owns rows rA, rA+64, global k-quad g (8 bf16 = 32B f32)
    const int rA = tid >> 2;
    const int g  = tid & 3;
    const int jA = g ^ ((rA >> 1) & 3);              // swizzled LDS quad slot
    float sc0 = 1.f, sc1 = 1.f;
    if (AF32) {
        sc0 = rowscale[m0 + rA];
        sc1 = rowscale[m0 + rA + 64];
    }
    const float* Af = (const float*)Ap;
    const unsigned short* Ab = (const unsigned short*)Ap;

    const int rslot = (lkg ^ ((lrow >> 1) & 3)) * 8;

    f32x4 acc[4][4] = {};

    const int nk = K / TK;
    for (int kt = 0; kt < nk; ++kt) {
        const int k0 = kt * TK;

        // B: async global->LDS
        gload16(Bt + (size_t)(n0 + r0) * K + k0 + q0 * 8, ldsB0);
        gload16(Bt + (size_t)(n0 + r1) * K + k0 + q1 * 8, ldsB1);

        if (AF32) {
            const float* pa0 = Af + (size_t)(m0 + rA) * K + k0 + g * 8;
            const float* pa1 = Af + (size_t)(m0 + rA + 64) * K + k0 + g * 8;
            float4 u0 = *reinterpret_cast<const float4*>(pa0);
            float4 u1 = *reinterpret_cast<const float4*>(pa0 + 4);
            float4 w0 = *reinterpret_cast<const float4*>(pa1);
            float4 w1 = *reinterpret_cast<const float4*>(pa1 + 4);
            short8 pk0, pk1;
            pk0[0] = (short)f2bf(u0.x * sc0); pk0[1] = (short)f2bf(u0.y * sc0);
            pk0[2] = (short)f2bf(u0.z * sc0); pk0[3] = (short)f2bf(u0.w * sc0);
            pk0[4] = (short)f2bf(u1.x * sc0); pk0[5] = (short)f2bf(u1.y * sc0);
            pk0[6] = (short)f2bf(u1.z * sc0); pk0[7] = (short)f2bf(u1.w * sc0);
            pk1[0] = (short)f2bf(w0.x * sc1); pk1[1] = (short)f2bf(w0.y * sc1);
            pk1[2] = (short)f2bf(w0.z * sc1); pk1[3] = (short)f2bf(w0.w * sc1);
            pk1[4] = (short)f2bf(w1.x * sc1); pk1[5] = (short)f2bf(w1.y * sc1);
            pk1[6] = (short)f2bf(w1.z * sc1); pk1[7] = (short)f2bf(w1.w * sc1);
            *reinterpret_cast<short8*>(AsB + rA * 64 + jA * 16) = pk0;
            *reinterpret_cast<short8*>(AsB + (rA + 64) * 64 + jA * 16) = pk1;
        } else {
            gload16(Ab + (size_t)(m0 + r0) * K + k0 + q0 * 8, ldsA0);
            gload16(Ab + (size_t)(m0 + r1) * K + k0 + q1 * 8, ldsA1);
        }
        __syncthreads();   // drains vmcnt + lgkmcnt before LDS reads

        short8 af[4], bfr[4];
        #pragma unroll
        for (int mi = 0; mi < 4; ++mi)
            af[mi] = *reinterpret_cast<const short8*>(&As[wr * 64 + mi * 16 + lrow][rslot]);
        #pragma unroll
        for (int ni = 0; ni < 4; ++ni)
            bfr[ni] = *reinterpret_cast<const short8*>(&Bs[wc * 64 + ni * 16 + lrow][rslot]);

        #pragma unroll
        for (int mi = 0; mi < 4; ++mi)
            #pragma unroll
            for (int ni = 0; ni < 4; ++ni)
                acc[mi][ni] = __builtin_amdgcn_mfma_f32_16x16x32_bf16(
                    af[mi], bfr[ni], acc[mi][ni], 0, 0, 0);

        __syncthreads();
    }

    #pragma unroll
    for (int mi = 0; mi < 4; ++mi)
        #pragma unroll
        for (int ni = 0; ni < 4; ++ni)
            #pragma unroll
            for (int r = 0; r < 4; ++r)
                Cb[(size_t)(m0 + wr * 64 + mi * 16 + lkg * 4 + r) * Nc
                   + (n0 + wc * 64 + ni * 16 + lrow)] = f2bf(acc[mi][ni][r]);
}

// ---------------- CSR gather-aggregate (bf16 X), fused epilogues ----------------

template<int DIM, bool LAYER1>
__global__ __launch_bounds__(256) void aggregate(
    const int* __restrict__ row_start, const int* __restrict__ eidx,
    const unsigned short* __restrict__ Xb, const float* __restrict__ isi,
    const float* __restrict__ iso, const float* __restrict__ bias,
    unsigned short* __restrict__ out_bf, float* __restrict__ out_f)
{
    constexpr int F = DIM / 64;           // 8 (HID) or 4 (OUTD)
    using VecT = typename VecSel<F>::T;
    const int node = blockIdx.x * 4 + (threadIdx.x >> 6);
    const int lane = threadIdx.x & 63;

    const int beg = row_start[node];
    const int end = row_start[node + 1];
    const unsigned short* base = Xb + lane * F;

    float acc[F] = {};
    int e = beg;
    for (; e + 1 < end; e += 2) {
        int i0 = eidx[e], i1 = eidx[e + 1];
        VecT v0 = *reinterpret_cast<const VecT*>(base + (size_t)i0 * DIM);
        VecT v1 = *reinterpret_cast<const VecT*>(base + (size_t)i1 * DIM);
        #pragma unroll
        for (int f = 0; f < F; ++f) { acc[f] += bf2f(v0[f]); acc[f] += bf2f(v1[f]); }
    }
    if (e < end) {
        VecT v0 = *reinterpret_cast<const VecT*>(base + (size_t)eidx[e] * DIM);
        #pragma unroll
        for (int f = 0; f < F; ++f) acc[f] += bf2f(v0[f]);
    }

    const float si = isi[node];
    float bv[F];
    #pragma unroll
    for (int q = 0; q < F / 4; ++q)
        *reinterpret_cast<float4*>(&bv[q * 4]) =
            *reinterpret_cast<const float4*>(bias + lane * F + q * 4);

    if (LAYER1) {
        const float so = iso[node];
        short8 o;
        #pragma unroll
        for (int f = 0; f < F; ++f) {
            float v = acc[f] * si + bv[f];
            v = v > 0.f ? v : expm1f(v);
            o[f] = (short)f2bf(v * so);
        }
        *reinterpret_cast<short8*>(out_bf + (size_t)node * DIM + lane * F) = o;
    } else {
        #pragma unroll
        for (int q = 0; q < F / 4; ++q) {
            float4 v = make_float4(acc[q * 4 + 0] * si + bv[q * 4 + 0],
                                   acc[q * 4 + 1] * si + bv[q * 4 + 1],
                                   acc[q * 4 + 2] * si + bv[q * 4 + 2],
                                   acc[q * 4 + 3] * si + bv[q * 4 + 3]);
            *reinterpret_cast<float4*>(out_f + (size_t)node * DIM + lane * F + q * 4) = v;
        }
    }
}

// ---------------- launch ----------------

extern "C" void kernel_launch(void* const* d_in, const int* in_sizes, int n_in,
                              void* d_out, int out_size, void* d_ws, size_t ws_size,
                              hipStream_t stream) {
    const float* h  = (const float*)d_in[0];
    const float* W1 = (const float*)d_in[1];
    const float* b1 = (const float*)d_in[2];
    const float* W2 = (const float*)d_in[3];
    const float* b2 = (const float*)d_in[4];
    const int*   src = (const int*)d_in[5];
    const int*   dst = (const int*)d_in[6];

    const int N = in_sizes[0] / IN_DIM;   // 65536
    const int E = in_sizes[5];            // 524288
    float* out = (float*)d_out;

    // ---- workspace layout ----
    int* dego      = (int*)d_ws;                   // N
    int* degi      = dego + N;                     // N
    int* excl      = degi + N;                     // N
    int* partials  = excl + N;                     // 256
    int* row_start = partials + 256;               // N+1 (pad to N+64)
    int* cursor    = row_start + N + 64;           // N
    int* eidx      = cursor + N;                   // E
    float* iso     = (float*)(eidx + E);           // N
    float* isi     = iso + N;                      // N
    unsigned short* W1t = (unsigned short*)(isi + N);      // IN_DIM*HID
    unsigned short* W2t = W1t + (size_t)IN_DIM * HID;      // HID*OUTD
    unsigned short* X1b = W2t + (size_t)HID * OUTD;        // N*HID bf16 (67MB)
    unsigned short* X2b = X1b;                             // alias (X1 dead before gemm2 write)
    unsigned short* R2h = X1b + (size_t)N * HID;           // N*HID bf16 (67MB) — x1s

    hipMemsetAsync(dego, 0, sizeof(int) * (size_t)2 * N, stream);

    deg_kernel<<<(E + 255) / 256, 256, 0, stream>>>(src, dst, dego, degi, E);
    invsqrt_kernel<<<(N + 255) / 256, 256, 0, stream>>>(dego, degi, iso, isi, N);

    // CSR by dst
    scan_block<<<N / 256, 256, 0, stream>>>(degi, excl, partials);
    scan_partials<<<1, 256, 0, stream>>>(partials);
    scan_add<<<N / 256, 256, 0, stream>>>(excl, partials, degi, row_start, cursor, N);
    csr_fill<<<(E + 255) / 256, 256, 0, stream>>>(src, dst, cursor, eidx, E);

    // weights -> bf16 transposed
    transpose_cvt<<<(IN_DIM * HID + 255) / 256, 256, 0, stream>>>(W1, W1t, IN_DIM, HID);
    transpose_cvt<<<(HID * OUTD + 255) / 256, 256, 0, stream>>>(W2, W2t, HID, OUTD);

    // Layer 1: X1b = bf16((iso⊙h) @ W1)  [scale+cvt fused into A-staging]
    dim3 g1(HID / TN, N / TM);
    gemm_bf16_mfma<1><<<g1, 256, 0, stream>>>(h, W1t, iso, X1b, N, IN_DIM, HID);
    aggregate<HID, true><<<N / 4, 256, 0, stream>>>(
        row_start, eidx, X1b, isi, iso, b1, R2h, nullptr);

    // Layer 2: X2b = bf16(R2h @ W2) ; out = agg(X2b)*isi + b2
    dim3 g2(OUTD / TN, N / TM);
    gemm_bf16_mfma<0><<<g2, 256, 0, stream>>>(R2h, W2t, nullptr, X2b, N, HID, OUTD);
    aggregate<OUTD, false><<<N / 4, 256, 0, stream>>>(
        row_start, eidx, X2b, isi, iso, b2, nullptr, out);
}

// Round 6
// 407.200 us; speedup vs baseline: 6.7839x; 1.0376x over previous
//
#include <hip/hip_runtime.h>
#include <hip/hip_bf16.h>

#define IN_DIM 1024
#define HID 512
#define OUTD 256

typedef __attribute__((ext_vector_type(8))) short short8;
typedef __attribute__((ext_vector_type(4))) float f32x4;
typedef __attribute__((ext_vector_type(8))) unsigned short ushort8e;
typedef __attribute__((ext_vector_type(4))) unsigned short ushort4e;

template<int F> struct VecSel;
template<> struct VecSel<8> { using T = ushort8e; };
template<> struct VecSel<4> { using T = ushort4e; };

// ---------------- helpers ----------------

__device__ inline unsigned short f2bf(float f) {
    union { float f; unsigned u; } v; v.f = f;
    unsigned r = (v.u + 0x7FFF + ((v.u >> 16) & 1)) >> 16;  // RNE
    return (unsigned short)r;
}

__device__ inline float bf2f(unsigned short u) {
    union { unsigned u; float f; } v; v.u = ((unsigned)u) << 16; return v.f;
}

__device__ inline void gload16(const void* g, void* l) {
    __builtin_amdgcn_global_load_lds(
        (const __attribute__((address_space(1))) void*)g,
        (__attribute__((address_space(3))) void*)l, 16, 0, 0);
}

// ---------------- degree / norm ----------------

__global__ void deg_kernel(const int* __restrict__ src, const int* __restrict__ dst,
                           int* __restrict__ dego, int* __restrict__ degi, int E) {
    int i = blockIdx.x * blockDim.x + threadIdx.x;
    if (i < E) {
        atomicAdd(&dego[src[i]], 1);
        atomicAdd(&degi[dst[i]], 1);
    }
}

__global__ void invsqrt_kernel(const int* __restrict__ dego, const int* __restrict__ degi,
                               float* __restrict__ iso, float* __restrict__ isi, int n) {
    int i = blockIdx.x * blockDim.x + threadIdx.x;
    if (i < n) {
        iso[i] = rsqrtf(fmaxf((float)dego[i], 1.0f));
        isi[i] = rsqrtf(fmaxf((float)degi[i], 1.0f));
    }
}

// ---------------- exclusive scan over N=65536 (256 blocks x 256) ----------------

__global__ __launch_bounds__(256) void scan_block(const int* __restrict__ deg,
                                                  int* __restrict__ excl,
                                                  int* __restrict__ partials) {
    __shared__ int tmp[256];
    int tid = threadIdx.x;
    int i = blockIdx.x * 256 + tid;
    int v = deg[i];
    tmp[tid] = v;
    __syncthreads();
    #pragma unroll
    for (int off = 1; off < 256; off <<= 1) {
        int t = (tid >= off) ? tmp[tid - off] : 0;
        __syncthreads();
        tmp[tid] += t;
        __syncthreads();
    }
    excl[i] = tmp[tid] - v;
    if (tid == 255) partials[blockIdx.x] = tmp[255];
}

__global__ __launch_bounds__(256) void scan_partials(int* __restrict__ partials) {
    __shared__ int tmp[256];
    int tid = threadIdx.x;
    int v = partials[tid];
    tmp[tid] = v;
    __syncthreads();
    #pragma unroll
    for (int off = 1; off < 256; off <<= 1) {
        int t = (tid >= off) ? tmp[tid - off] : 0;
        __syncthreads();
        tmp[tid] += t;
        __syncthreads();
    }
    partials[tid] = tmp[tid] - v;   // exclusive
}

__global__ __launch_bounds__(256) void scan_add(const int* __restrict__ excl,
                                                const int* __restrict__ partials,
                                                const int* __restrict__ deg,
                                                int* __restrict__ row_start,
                                                int* __restrict__ cursor, int n) {
    int i = blockIdx.x * 256 + threadIdx.x;
    int v = excl[i] + partials[blockIdx.x];
    row_start[i] = v;
    cursor[i] = v;
    if (i == n - 1) row_start[n] = v + deg[i];
}

__global__ void csr_fill(const int* __restrict__ src, const int* __restrict__ dst,
                         int* __restrict__ cursor, int* __restrict__ eidx, int E) {
    int e = blockIdx.x * blockDim.x + threadIdx.x;
    if (e < E) {
        int pos = atomicAdd(&cursor[dst[e]], 1);
        eidx[pos] = src[e];
    }
}

// ---------------- weight transpose+cvt ----------------

__global__ void transpose_cvt(const float* __restrict__ W, unsigned short* __restrict__ Wt,
                              int K, int N) {
    int i = blockIdx.x * 256 + threadIdx.x;
    if (i < N * K) {
        int n = i / K, k = i - n * K;
        Wt[i] = f2bf(W[(size_t)k * N + n]);
    }
}

// ---------------- bf16 MFMA GEMM: C = A[M,K] @ Bt[Nc,K]^T, bf16 output ----------------
// 1-D grid, XCD-aware swizzle: sibling column-blocks of one A-panel run
// consecutively on the SAME XCD so the A-panel is an L2 hit for 3 of 4 blocks.
// AF32=1: A is f32, scaled by rowscale[row], cvt to bf16 during reg-staging.
// AF32=0: A is bf16, staged via global_load_lds.

#define TM 128
#define TN 128
#define TK 32
#define NXCD 8

template<int AF32>
__global__ __launch_bounds__(256) void gemm_bf16_mfma(
    const void* __restrict__ Ap, const unsigned short* __restrict__ Bt,
    const float* __restrict__ rowscale, unsigned short* __restrict__ Cb,
    int M, int K, int Nc)
{
    __shared__ unsigned short As[TM][TK];
    __shared__ unsigned short Bs[TN][TK];

    const int tid  = threadIdx.x;
    const int lane = tid & 63;
    const int wave = tid >> 6;
    const int wr = wave >> 1, wc = wave & 1;
    const int lrow = lane & 15;
    const int lkg  = lane >> 4;

    // ---- XCD swizzle: lin -> (xcd, idx) -> newlin; siblings share m-panel ----
    const int nwg = gridDim.x;                // divisible by 8
    const int per = nwg / NXCD;
    const int lin = blockIdx.x;
    const int newlin = (lin % NXCD) * per + lin / NXCD;
    const int ncb = Nc / TN;                  // column blocks (4 or 2)
    const int m0 = (newlin / ncb) * TM;
    const int n0 = (newlin % ncb) * TN;

    const int s0 = wave * 64 + lane;
    const int s1 = s0 + 256;
    const int r0 = s0 >> 2, q0 = (s0 & 3) ^ ((s0 >> 3) & 3);
    const int r1 = s1 >> 2, q1 = (s1 & 3) ^ ((s1 >> 3) & 3);

    char* AsB = (char*)&As[0][0];
    char* BsB = (char*)&Bs[0][0];
    void* ldsA0 = AsB + wave * 1024;
    void* ldsA1 = AsB + 4096 + wave * 1024;
    void* ldsB0 = BsB + wave * 1024;
    void* ldsB1 = BsB + 4096 + wave * 1024;

    // AF32 reg-staging: thread owns rows rA, rA+64, global k-quad g (8 bf16 = 32B f32)
    const int rA = tid >> 2;
    const int g  = tid & 3;
    const int jA = g ^ ((rA >> 1) & 3);              // swizzled LDS quad slot
    float sc0 = 1.f, sc1 = 1.f;
    if (AF32) {
        sc0 = rowscale[m0 + rA];
        sc1 = rowscale[m0 + rA + 64];
    }
    const float* Af = (const float*)Ap;
    const unsigned short* Ab = (const unsigned short*)Ap;

    const int rslot = (lkg ^ ((lrow >> 1) & 3)) * 8;

    f32x4 acc[4][4] = {};

    const int nk = K / TK;
    for (int kt = 0; kt < nk; ++kt) {
        const int k0 = kt * TK;

        // B: async global->LDS
        gload16(Bt + (size_t)(n0 + r0) * K + k0 + q0 * 8, ldsB0);
        gload16(Bt + (size_t)(n0 + r1) * K + k0 + q1 * 8, ldsB1);

        if (AF32) {
            const float* pa0 = Af + (size_t)(m0 + rA) * K + k0 + g * 8;
            const float* pa1 = Af + (size_t)(m0 + rA + 64) * K + k0 + g * 8;
            float4 u0 = *reinterpret_cast<const float4*>(pa0);
            float4 u1 = *reinterpret_cast<const float4*>(pa0 + 4);
            float4 w0 = *reinterpret_cast<const float4*>(pa1);
            float4 w1 = *reinterpret_cast<const float4*>(pa1 + 4);
            short8 pk0, pk1;
            pk0[0] = (short)f2bf(u0.x * sc0); pk0[1] = (short)f2bf(u0.y * sc0);
            pk0[2] = (short)f2bf(u0.z * sc0); pk0[3] = (short)f2bf(u0.w * sc0);
            pk0[4] = (short)f2bf(u1.x * sc0); pk0[5] = (short)f2bf(u1.y * sc0);
            pk0[6] = (short)f2bf(u1.z * sc0); pk0[7] = (short)f2bf(u1.w * sc0);
            pk1[0] = (short)f2bf(w0.x * sc1); pk1[1] = (short)f2bf(w0.y * sc1);
            pk1[2] = (short)f2bf(w0.z * sc1); pk1[3] = (short)f2bf(w0.w * sc1);
            pk1[4] = (short)f2bf(w1.x * sc1); pk1[5] = (short)f2bf(w1.y * sc1);
            pk1[6] = (short)f2bf(w1.z * sc1); pk1[7] = (short)f2bf(w1.w * sc1);
            *reinterpret_cast<short8*>(AsB + rA * 64 + jA * 16) = pk0;
            *reinterpret_cast<short8*>(AsB + (rA + 64) * 64 + jA * 16) = pk1;
        } else {
            gload16(Ab + (size_t)(m0 + r0) * K + k0 + q0 * 8, ldsA0);
            gload16(Ab + (size_t)(m0 + r1) * K + k0 + q1 * 8, ldsA1);
        }
        __syncthreads();   // drains vmcnt + lgkmcnt before LDS reads

        short8 af[4], bfr[4];
        #pragma unroll
        for (int mi = 0; mi < 4; ++mi)
            af[mi] = *reinterpret_cast<const short8*>(&As[wr * 64 + mi * 16 + lrow][rslot]);
        #pragma unroll
        for (int ni = 0; ni < 4; ++ni)
            bfr[ni] = *reinterpret_cast<const short8*>(&Bs[wc * 64 + ni * 16 + lrow][rslot]);

        #pragma unroll
        for (int mi = 0; mi < 4; ++mi)
            #pragma unroll
            for (int ni = 0; ni < 4; ++ni)
                acc[mi][ni] = __builtin_amdgcn_mfma_f32_16x16x32_bf16(
                    af[mi], bfr[ni], acc[mi][ni], 0, 0, 0);

        __syncthreads();
    }

    #pragma unroll
    for (int mi = 0; mi < 4; ++mi)
        #pragma unroll
        for (int ni = 0; ni < 4; ++ni)
            #pragma unroll
            for (int r = 0; r < 4; ++r)
                Cb[(size_t)(m0 + wr * 64 + mi * 16 + lkg * 4 + r) * Nc
                   + (n0 + wc * 64 + ni * 16 + lrow)] = f2bf(acc[mi][ni][r]);
}

// ---------------- CSR gather-aggregate (bf16 X), fused epilogues ----------------

template<int DIM, bool LAYER1>
__global__ __launch_bounds__(256) void aggregate(
    const int* __restrict__ row_start, const int* __restrict__ eidx,
    const unsigned short* __restrict__ Xb, const float* __restrict__ isi,
    const float* __restrict__ iso, const float* __restrict__ bias,
    unsigned short* __restrict__ out_bf, float* __restrict__ out_f)
{
    constexpr int F = DIM / 64;           // 8 (HID) or 4 (OUTD)
    using VecT = typename VecSel<F>::T;
    const int node = blockIdx.x * 4 + (threadIdx.x >> 6);
    const int lane = threadIdx.x & 63;

    const int beg = row_start[node];
    const int end = row_start[node + 1];
    const unsigned short* base = Xb + lane * F;

    float acc[F] = {};
    int e = beg;
    for (; e + 1 < end; e += 2) {
        int i0 = eidx[e], i1 = eidx[e + 1];
        VecT v0 = *reinterpret_cast<const VecT*>(base + (size_t)i0 * DIM);
        VecT v1 = *reinterpret_cast<const VecT*>(base + (size_t)i1 * DIM);
        #pragma unroll
        for (int f = 0; f < F; ++f) { acc[f] += bf2f(v0[f]); acc[f] += bf2f(v1[f]); }
    }
    if (e < end) {
        VecT v0 = *reinterpret_cast<const VecT*>(base + (size_t)eidx[e] * DIM);
        #pragma unroll
        for (int f = 0; f < F; ++f) acc[f] += bf2f(v0[f]);
    }

    const float si = isi[node];
    float bv[F];
    #pragma unroll
    for (int q = 0; q < F / 4; ++q)
        *reinterpret_cast<float4*>(&bv[q * 4]) =
            *reinterpret_cast<const float4*>(bias + lane * F + q * 4);

    if (LAYER1) {
        const float so = iso[node];
        short8 o;
        #pragma unroll
        for (int f = 0; f < F; ++f) {
            float v = acc[f] * si + bv[f];
            v = v > 0.f ? v : expm1f(v);
            o[f] = (short)f2bf(v * so);
        }
        *reinterpret_cast<short8*>(out_bf + (size_t)node * DIM + lane * F) = o;
    } else {
        #pragma unroll
        for (int q = 0; q < F / 4; ++q) {
            float4 v = make_float4(acc[q * 4 + 0] * si + bv[q * 4 + 0],
                                   acc[q * 4 + 1] * si + bv[q * 4 + 1],
                                   acc[q * 4 + 2] * si + bv[q * 4 + 2],
                                   acc[q * 4 + 3] * si + bv[q * 4 + 3]);
            *reinterpret_cast<float4*>(out_f + (size_t)node * DIM + lane * F + q * 4) = v;
        }
    }
}

// ---------------- launch ----------------

extern "C" void kernel_launch(void* const* d_in, const int* in_sizes, int n_in,
                              void* d_out, int out_size, void* d_ws, size_t ws_size,
                              hipStream_t stream) {
    const float* h  = (const float*)d_in[0];
    const float* W1 = (const float*)d_in[1];
    const float* b1 = (const float*)d_in[2];
    const float* W2 = (const float*)d_in[3];
    const float* b2 = (const float*)d_in[4];
    const int*   src = (const int*)d_in[5];
    const int*   dst = (const int*)d_in[6];

    const int N = in_sizes[0] / IN_DIM;   // 65536
    const int E = in_sizes[5];            // 524288
    float* out = (float*)d_out;

    // ---- workspace layout ----
    int* dego      = (int*)d_ws;                   // N
    int* degi      = dego + N;                     // N
    int* excl      = degi + N;                     // N
    int* partials  = excl + N;                     // 256
    int* row_start = partials + 256;               // N+1 (pad to N+64)
    int* cursor    = row_start + N + 64;           // N
    int* eidx      = cursor + N;                   // E
    float* iso     = (float*)(eidx + E);           // N
    float* isi     = iso + N;                      // N
    unsigned short* W1t = (unsigned short*)(isi + N);      // IN_DIM*HID
    unsigned short* W2t = W1t + (size_t)IN_DIM * HID;      // HID*OUTD
    unsigned short* X1b = W2t + (size_t)HID * OUTD;        // N*HID bf16 (67MB)
    unsigned short* X2b = X1b;                             // alias (X1 dead before gemm2 write)
    unsigned short* R2h = X1b + (size_t)N * HID;           // N*HID bf16 (67MB) — x1s

    hipMemsetAsync(dego, 0, sizeof(int) * (size_t)2 * N, stream);

    deg_kernel<<<(E + 255) / 256, 256, 0, stream>>>(src, dst, dego, degi, E);
    invsqrt_kernel<<<(N + 255) / 256, 256, 0, stream>>>(dego, degi, iso, isi, N);

    // CSR by dst
    scan_block<<<N / 256, 256, 0, stream>>>(degi, excl, partials);
    scan_partials<<<1, 256, 0, stream>>>(partials);
    scan_add<<<N / 256, 256, 0, stream>>>(excl, partials, degi, row_start, cursor, N);
    csr_fill<<<(E + 255) / 256, 256, 0, stream>>>(src, dst, cursor, eidx, E);

    // weights -> bf16 transposed
    transpose_cvt<<<(IN_DIM * HID + 255) / 256, 256, 0, stream>>>(W1, W1t, IN_DIM, HID);
    transpose_cvt<<<(HID * OUTD + 255) / 256, 256, 0, stream>>>(W2, W2t, HID, OUTD);

    // Layer 1: X1b = bf16((iso⊙h) @ W1)  [scale+cvt fused into A-staging]
    gemm_bf16_mfma<1><<<(N / TM) * (HID / TN), 256, 0, stream>>>(
        h, W1t, iso, X1b, N, IN_DIM, HID);
    aggregate<HID, true><<<N / 4, 256, 0, stream>>>(
        row_start, eidx, X1b, isi, iso, b1, R2h, nullptr);

    // Layer 2: X2b = bf16(R2h @ W2) ; out = agg(X2b)*isi + b2
    gemm_bf16_mfma<0><<<(N / TM) * (OUTD / TN), 256, 0, stream>>>(
        R2h, W2t, nullptr, X2b, N, HID, OUTD);
    aggregate<OUTD, false><<<N / 4, 256, 0, stream>>>(
        row_start, eidx, X2b, isi, iso, b2, nullptr, out);
}

// Round 7
// 404.675 us; speedup vs baseline: 6.8263x; 1.0062x over previous
//
#include <hip/hip_runtime.h>
#include <hip/hip_bf16.h>

#define IN_DIM 1024
#define HID 512
#define OUTD 256

typedef __attribute__((ext_vector_type(8))) short short8;
typedef __attribute__((ext_vector_type(4))) float f32x4;
typedef __attribute__((ext_vector_type(8))) unsigned short ushort8e;
typedef __attribute__((ext_vector_type(4))) unsigned short ushort4e;

template<int F> struct VecSel;
template<> struct VecSel<8> { using T = ushort8e; };
template<> struct VecSel<4> { using T = ushort4e; };

// ---------------- helpers ----------------

__device__ inline unsigned short f2bf(float f) {
    union { float f; unsigned u; } v; v.f = f;
    unsigned r = (v.u + 0x7FFF + ((v.u >> 16) & 1)) >> 16;  // RNE
    return (unsigned short)r;
}

__device__ inline float bf2f(unsigned short u) {
    union { unsigned u; float f; } v; v.u = ((unsigned)u) << 16; return v.f;
}

__device__ inline void gload16(const void* g, void* l) {
    __builtin_amdgcn_global_load_lds(
        (const __attribute__((address_space(1))) void*)g,
        (__attribute__((address_space(3))) void*)l, 16, 0, 0);
}

// ---------------- degree / norm ----------------

__global__ void deg_kernel(const int* __restrict__ src, const int* __restrict__ dst,
                           int* __restrict__ dego, int* __restrict__ degi, int E) {
    int i = blockIdx.x * blockDim.x + threadIdx.x;
    if (i < E) {
        atomicAdd(&dego[src[i]], 1);
        atomicAdd(&degi[dst[i]], 1);
    }
}

__global__ void invsqrt_kernel(const int* __restrict__ dego, const int* __restrict__ degi,
                               float* __restrict__ iso, float* __restrict__ isi, int n) {
    int i = blockIdx.x * blockDim.x + threadIdx.x;
    if (i < n) {
        iso[i] = rsqrtf(fmaxf((float)dego[i], 1.0f));
        isi[i] = rsqrtf(fmaxf((float)degi[i], 1.0f));
    }
}

// ---------------- exclusive scan over N=65536 (256 blocks x 256) ----------------

__global__ __launch_bounds__(256) void scan_block(const int* __restrict__ deg,
                                                  int* __restrict__ excl,
                                                  int* __restrict__ partials) {
    __shared__ int tmp[256];
    int tid = threadIdx.x;
    int i = blockIdx.x * 256 + tid;
    int v = deg[i];
    tmp[tid] = v;
    __syncthreads();
    #pragma unroll
    for (int off = 1; off < 256; off <<= 1) {
        int t = (tid >= off) ? tmp[tid - off] : 0;
        __syncthreads();
        tmp[tid] += t;
        __syncthreads();
    }
    excl[i] = tmp[tid] - v;
    if (tid == 255) partials[blockIdx.x] = tmp[255];
}

__global__ __launch_bounds__(256) void scan_partials(int* __restrict__ partials) {
    __shared__ int tmp[256];
    int tid = threadIdx.x;
    int v = partials[tid];
    tmp[tid] = v;
    __syncthreads();
    #pragma unroll
    for (int off = 1; off < 256; off <<= 1) {
        int t = (tid >= off) ? tmp[tid - off] : 0;
        __syncthreads();
        tmp[tid] += t;
        __syncthreads();
    }
    partials[tid] = tmp[tid] - v;   // exclusive
}

__global__ __launch_bounds__(256) void scan_add(const int* __restrict__ excl,
                                                const int* __restrict__ partials,
                                                const int* __restrict__ deg,
                                                int* __restrict__ row_start,
                                                int* __restrict__ cursor, int n) {
    int i = blockIdx.x * 256 + threadIdx.x;
    int v = excl[i] + partials[blockIdx.x];
    row_start[i] = v;
    cursor[i] = v;
    if (i == n - 1) row_start[n] = v + deg[i];
}

__global__ void csr_fill(const int* __restrict__ src, const int* __restrict__ dst,
                         int* __restrict__ cursor, int* __restrict__ eidx, int E) {
    int e = blockIdx.x * blockDim.x + threadIdx.x;
    if (e < E) {
        int pos = atomicAdd(&cursor[dst[e]], 1);
        eidx[pos] = src[e];
    }
}

// ---------------- weight transpose+cvt ----------------

__global__ void transpose_cvt(const float* __restrict__ W, unsigned short* __restrict__ Wt,
                              int K, int N) {
    int i = blockIdx.x * 256 + threadIdx.x;
    if (i < N * K) {
        int n = i / K, k = i - n * K;
        Wt[i] = f2bf(W[(size_t)k * N + n]);
    }
}

// ---------------- bf16 MFMA GEMM: C = A[M,K] @ Bt[Nc,K]^T, bf16 output ----------------
// Double-buffered single-barrier K-loop. XCD-aware block swizzle.
// AF32=1: A is f32, scaled by rowscale[row]; f32 loads for tile t+1 issued
//         before tile t's MFMA (latency hidden), cvt+ds_write after MFMA.
// AF32=0: A is bf16 via global_load_lds (wave-uniform dest).

#define TM 128
#define TN 128
#define TK 32
#define NXCD 8

struct ARegs { float4 u0, u1, w0, w1; };

template<int AF32>
__global__ __launch_bounds__(256) void gemm_bf16_mfma(
    const void* __restrict__ Ap, const unsigned short* __restrict__ Bt,
    const float* __restrict__ rowscale, unsigned short* __restrict__ Cb,
    int M, int K, int Nc)
{
    __shared__ unsigned short As[2][TM][TK];   // 2 x 8 KB
    __shared__ unsigned short Bs[2][TN][TK];   // 2 x 8 KB

    const int tid  = threadIdx.x;
    const int lane = tid & 63;
    const int wave = tid >> 6;
    const int wr = wave >> 1, wc = wave & 1;
    const int lrow = lane & 15;
    const int lkg  = lane >> 4;

    // ---- XCD swizzle: siblings sharing an A-panel run on the same XCD ----
    const int nwg = gridDim.x;                // divisible by 8
    const int per = nwg / NXCD;
    const int lin = blockIdx.x;
    const int newlin = (lin % NXCD) * per + lin / NXCD;
    const int ncb = Nc / TN;
    const int m0 = (newlin / ncb) * TM;
    const int n0 = (newlin % ncb) * TN;

    const int s0 = wave * 64 + lane;
    const int s1 = s0 + 256;
    const int r0 = s0 >> 2, q0 = (s0 & 3) ^ ((s0 >> 3) & 3);
    const int r1 = s1 >> 2, q1 = (s1 & 3) ^ ((s1 >> 3) & 3);

    char* AsB = (char*)&As[0][0][0];
    char* BsB = (char*)&Bs[0][0][0];

    // AF32 reg-staging geometry: thread owns rows rA, rA+64, k-quad g
    const int rA = tid >> 2;
    const int g  = tid & 3;
    const int jA = g ^ ((rA >> 1) & 3);       // swizzled LDS quad slot
    float sc0 = 1.f, sc1 = 1.f;
    if (AF32) {
        sc0 = rowscale[m0 + rA];
        sc1 = rowscale[m0 + rA + 64];
    }
    const float* Af = (const float*)Ap;
    const unsigned short* Ab = (const unsigned short*)Ap;

    const int rslot = (lkg ^ ((lrow >> 1) & 3)) * 8;

    auto stageB = [&](int kt, int buf) {
        const int k0 = kt * TK;
        gload16(Bt + (size_t)(n0 + r0) * K + k0 + q0 * 8, BsB + buf * 8192 + wave * 1024);
        gload16(Bt + (size_t)(n0 + r1) * K + k0 + q1 * 8, BsB + buf * 8192 + 4096 + wave * 1024);
    };
    auto stageA_lds = [&](int kt, int buf) {
        const int k0 = kt * TK;
        gload16(Ab + (size_t)(m0 + r0) * K + k0 + q0 * 8, AsB + buf * 8192 + wave * 1024);
        gload16(Ab + (size_t)(m0 + r1) * K + k0 + q1 * 8, AsB + buf * 8192 + 4096 + wave * 1024);
    };
    auto loadA = [&](int kt, ARegs& r) {
        const float* pa0 = Af + (size_t)(m0 + rA) * K + kt * TK + g * 8;
        const float* pa1 = pa0 + (size_t)64 * K;
        r.u0 = *reinterpret_cast<const float4*>(pa0);
        r.u1 = *reinterpret_cast<const float4*>(pa0 + 4);
        r.w0 = *reinterpret_cast<const float4*>(pa1);
        r.w1 = *reinterpret_cast<const float4*>(pa1 + 4);
    };
    auto writeA = [&](int buf, const ARegs& r) {
        short8 pk0, pk1;
        pk0[0] = (short)f2bf(r.u0.x * sc0); pk0[1] = (short)f2bf(r.u0.y * sc0);
        pk0[2] = (short)f2bf(r.u0.z * sc0); pk0[3] = (short)f2bf(r.u0.w * sc0);
        pk0[4] = (short)f2bf(r.u1.x * sc0); pk0[5] = (short)f2bf(r.u1.y * sc0);
        pk0[6] = (short)f2bf(r.u1.z * sc0); pk0[7] = (short)f2bf(r.u1.w * sc0);
        pk1[0] = (short)f2bf(r.w0.x * sc1); pk1[1] = (short)f2bf(r.w0.y * sc1);
        pk1[2] = (short)f2bf(r.w0.z * sc1); pk1[3] = (short)f2bf(r.w0.w * sc1);
        pk1[4] = (short)f2bf(r.w1.x * sc1); pk1[5] = (short)f2bf(r.w1.y * sc1);
        pk1[6] = (short)f2bf(r.w1.z * sc1); pk1[7] = (short)f2bf(r.w1.w * sc1);
        *reinterpret_cast<short8*>(AsB + buf * 8192 + rA * 64 + jA * 16) = pk0;
        *reinterpret_cast<short8*>(AsB + buf * 8192 + (rA + 64) * 64 + jA * 16) = pk1;
    };

    f32x4 acc[4][4] = {};
    ARegs ar;

    // prologue: tile 0 into buffer 0
    stageB(0, 0);
    if (AF32) { loadA(0, ar); writeA(0, ar); }
    else       stageA_lds(0, 0);
    __syncthreads();

    const int nk = K / TK;
    for (int kt = 0; kt < nk; ++kt) {
        const int cur = kt & 1, nxt = cur ^ 1;

        // issue next tile's loads first (latency hides under MFMA)
        if (kt + 1 < nk) {
            stageB(kt + 1, nxt);
            if (AF32) loadA(kt + 1, ar);
            else      stageA_lds(kt + 1, nxt);
        }

        short8 af[4], bfr[4];
        #pragma unroll
        for (int mi = 0; mi < 4; ++mi)
            af[mi] = *reinterpret_cast<const short8*>(&As[cur][wr * 64 + mi * 16 + lrow][rslot]);
        #pragma unroll
        for (int ni = 0; ni < 4; ++ni)
            bfr[ni] = *reinterpret_cast<const short8*>(&Bs[cur][wc * 64 + ni * 16 + lrow][rslot]);

        #pragma unroll
        for (int mi = 0; mi < 4; ++mi)
            #pragma unroll
            for (int ni = 0; ni < 4; ++ni)
                acc[mi][ni] = __builtin_amdgcn_mfma_f32_16x16x32_bf16(
                    af[mi], bfr[ni], acc[mi][ni], 0, 0, 0);

        // convert + write next A tile after MFMA (loads have landed by now)
        if (AF32 && kt + 1 < nk) writeA(nxt, ar);

        __syncthreads();   // single barrier: drains vmcnt (B gload_lds) + orders LDS
    }

    #pragma unroll
    for (int mi = 0; mi < 4; ++mi)
        #pragma unroll
        for (int ni = 0; ni < 4; ++ni)
            #pragma unroll
            for (int r = 0; r < 4; ++r)
                Cb[(size_t)(m0 + wr * 64 + mi * 16 + lkg * 4 + r) * Nc
                   + (n0 + wc * 64 + ni * 16 + lrow)] = f2bf(acc[mi][ni][r]);
}

// ---------------- CSR gather-aggregate (bf16 X), fused epilogues ----------------

template<int DIM, bool LAYER1>
__global__ __launch_bounds__(256) void aggregate(
    const int* __restrict__ row_start, const int* __restrict__ eidx,
    const unsigned short* __restrict__ Xb, const float* __restrict__ isi,
    const float* __restrict__ iso, const float* __restrict__ bias,
    unsigned short* __restrict__ out_bf, float* __restrict__ out_f)
{
    constexpr int F = DIM / 64;           // 8 (HID) or 4 (OUTD)
    using VecT = typename VecSel<F>::T;
    const int node = blockIdx.x * 4 + (threadIdx.x >> 6);
    const int lane = threadIdx.x & 63;

    const int beg = row_start[node];
    const int end = row_start[node + 1];
    const unsigned short* base = Xb + lane * F;

    float acc[F] = {};
    int e = beg;
    for (; e + 1 < end; e += 2) {
        int i0 = eidx[e], i1 = eidx[e + 1];
        VecT v0 = *reinterpret_cast<const VecT*>(base + (size_t)i0 * DIM);
        VecT v1 = *reinterpret_cast<const VecT*>(base + (size_t)i1 * DIM);
        #pragma unroll
        for (int f = 0; f < F; ++f) { acc[f] += bf2f(v0[f]); acc[f] += bf2f(v1[f]); }
    }
    if (e < end) {
        VecT v0 = *reinterpret_cast<const VecT*>(base + (size_t)eidx[e] * DIM);
        #pragma unroll
        for (int f = 0; f < F; ++f) acc[f] += bf2f(v0[f]);
    }

    const float si = isi[node];
    float bv[F];
    #pragma unroll
    for (int q = 0; q < F / 4; ++q)
        *reinterpret_cast<float4*>(&bv[q * 4]) =
            *reinterpret_cast<const float4*>(bias + lane * F + q * 4);

    if (LAYER1) {
        const float so = iso[node];
        short8 o;
        #pragma unroll
        for (int f = 0; f < F; ++f) {
            float v = acc[f] * si + bv[f];
            v = v > 0.f ? v : expm1f(v);
            o[f] = (short)f2bf(v * so);
        }
        *reinterpret_cast<short8*>(out_bf + (size_t)node * DIM + lane * F) = o;
    } else {
        #pragma unroll
        for (int q = 0; q < F / 4; ++q) {
            float4 v = make_float4(acc[q * 4 + 0] * si + bv[q * 4 + 0],
                                   acc[q * 4 + 1] * si + bv[q * 4 + 1],
                                   acc[q * 4 + 2] * si + bv[q * 4 + 2],
                                   acc[q * 4 + 3] * si + bv[q * 4 + 3]);
            *reinterpret_cast<float4*>(out_f + (size_t)node * DIM + lane * F + q * 4) = v;
        }
    }
}

// ---------------- launch ----------------

extern "C" void kernel_launch(void* const* d_in, const int* in_sizes, int n_in,
                              void* d_out, int out_size, void* d_ws, size_t ws_size,
                              hipStream_t stream) {
    const float* h  = (const float*)d_in[0];
    const float* W1 = (const float*)d_in[1];
    const float* b1 = (const float*)d_in[2];
    const float* W2 = (const float*)d_in[3];
    const float* b2 = (const float*)d_in[4];
    const int*   src = (const int*)d_in[5];
    const int*   dst = (const int*)d_in[6];

    const int N = in_sizes[0] / IN_DIM;   // 65536
    const int E = in_sizes[5];            // 524288
    float* out = (float*)d_out;

    // ---- workspace layout ----
    int* dego      = (int*)d_ws;                   // N
    int* degi      = dego + N;                     // N
    int* excl      = degi + N;                     // N
    int* partials  = excl + N;                     // 256
    int* row_start = partials + 256;               // N+1 (pad to N+64)
    int* cursor    = row_start + N + 64;           // N
    int* eidx      = cursor + N;                   // E
    float* iso     = (float*)(eidx + E);           // N
    float* isi     = iso + N;                      // N
    unsigned short* W1t = (unsigned short*)(isi + N);      // IN_DIM*HID
    unsigned short* W2t = W1t + (size_t)IN_DIM * HID;      // HID*OUTD
    unsigned short* X1b = W2t + (size_t)HID * OUTD;        // N*HID bf16 (67MB)
    unsigned short* X2b = X1b;                             // alias (X1 dead before gemm2 write)
    unsigned short* R2h = X1b + (size_t)N * HID;           // N*HID bf16 (67MB) — x1s

    hipMemsetAsync(dego, 0, sizeof(int) * (size_t)2 * N, stream);

    deg_kernel<<<(E + 255) / 256, 256, 0, stream>>>(src, dst, dego, degi, E);
    invsqrt_kernel<<<(N + 255) / 256, 256, 0, stream>>>(dego, degi, iso, isi, N);

    // CSR by dst
    scan_block<<<N / 256, 256, 0, stream>>>(degi, excl, partials);
    scan_partials<<<1, 256, 0, stream>>>(partials);
    scan_add<<<N / 256, 256, 0, stream>>>(excl, partials, degi, row_start, cursor, N);
    csr_fill<<<(E + 255) / 256, 256, 0, stream>>>(src, dst, cursor, eidx, E);

    // weights -> bf16 transposed
    transpose_cvt<<<(IN_DIM * HID + 255) / 256, 256, 0, stream>>>(W1, W1t, IN_DIM, HID);
    transpose_cvt<<<(HID * OUTD + 255) / 256, 256, 0, stream>>>(W2, W2t, HID, OUTD);

    // Layer 1: X1b = bf16((iso⊙h) @ W1)  [scale+cvt fused into A-staging]
    gemm_bf16_mfma<1><<<(N / TM) * (HID / TN), 256, 0, stream>>>(
        h, W1t, iso, X1b, N, IN_DIM, HID);
    aggregate<HID, true><<<N / 4, 256, 0, stream>>>(
        row_start, eidx, X1b, isi, iso, b1, R2h, nullptr);

    // Layer 2: X2b = bf16(R2h @ W2) ; out = agg(X2b)*isi + b2
    gemm_bf16_mfma<0><<<(N / TM) * (OUTD / TN), 256, 0, stream>>>(
        R2h, W2t, nullptr, X2b, N, HID, OUTD);
    aggregate<OUTD, false><<<N / 4, 256, 0, stream>>>(
        row_start, eidx, X2b, isi, iso, b2, nullptr, out);
}

// Round 8
// 399.425 us; speedup vs baseline: 6.9160x; 1.0131x over previous
//
#include <hip/hip_runtime.h>
#include <hip/hip_bf16.h>

#define IN_DIM 1024
#define HID 512
#define OUTD 256

typedef __attribute__((ext_vector_type(8))) short short8;
typedef __attribute__((ext_vector_type(4))) float f32x4;
typedef __attribute__((ext_vector_type(8))) unsigned short ushort8e;
typedef __attribute__((ext_vector_type(4))) unsigned short ushort4e;

template<int F> struct VecSel;
template<> struct VecSel<8> { using T = ushort8e; };
template<> struct VecSel<4> { using T = ushort4e; };

// ---------------- helpers ----------------

__device__ inline unsigned short f2bf(float f) {
    union { float f; unsigned u; } v; v.f = f;
    unsigned r = (v.u + 0x7FFF + ((v.u >> 16) & 1)) >> 16;  // RNE
    return (unsigned short)r;
}

__device__ inline float bf2f(unsigned short u) {
    union { unsigned u; float f; } v; v.u = ((unsigned)u) << 16; return v.f;
}

__device__ inline void gload16(const void* g, void* l) {
    __builtin_amdgcn_global_load_lds(
        (const __attribute__((address_space(1))) void*)g,
        (__attribute__((address_space(3))) void*)l, 16, 0, 0);
}

// ---------------- degree / norm ----------------

__global__ void deg_kernel(const int* __restrict__ src, const int* __restrict__ dst,
                           int* __restrict__ dego, int* __restrict__ degi, int E) {
    int i = blockIdx.x * blockDim.x + threadIdx.x;
    if (i < E) {
        atomicAdd(&dego[src[i]], 1);
        atomicAdd(&degi[dst[i]], 1);
    }
}

__global__ void invsqrt_kernel(const int* __restrict__ dego, const int* __restrict__ degi,
                               float* __restrict__ iso, float* __restrict__ isi, int n) {
    int i = blockIdx.x * blockDim.x + threadIdx.x;
    if (i < n) {
        iso[i] = rsqrtf(fmaxf((float)dego[i], 1.0f));
        isi[i] = rsqrtf(fmaxf((float)degi[i], 1.0f));
    }
}

// ---------------- exclusive scan over N=65536 (256 blocks x 256) ----------------

__global__ __launch_bounds__(256) void scan_block(const int* __restrict__ deg,
                                                  int* __restrict__ excl,
                                                  int* __restrict__ partials) {
    __shared__ int tmp[256];
    int tid = threadIdx.x;
    int i = blockIdx.x * 256 + tid;
    int v = deg[i];
    tmp[tid] = v;
    __syncthreads();
    #pragma unroll
    for (int off = 1; off < 256; off <<= 1) {
        int t = (tid >= off) ? tmp[tid - off] : 0;
        __syncthreads();
        tmp[tid] += t;
        __syncthreads();
    }
    excl[i] = tmp[tid] - v;
    if (tid == 255) partials[blockIdx.x] = tmp[255];
}

__global__ __launch_bounds__(256) void scan_partials(int* __restrict__ partials) {
    __shared__ int tmp[256];
    int tid = threadIdx.x;
    int v = partials[tid];
    tmp[tid] = v;
    __syncthreads();
    #pragma unroll
    for (int off = 1; off < 256; off <<= 1) {
        int t = (tid >= off) ? tmp[tid - off] : 0;
        __syncthreads();
        tmp[tid] += t;
        __syncthreads();
    }
    partials[tid] = tmp[tid] - v;   // exclusive
}

__global__ __launch_bounds__(256) void scan_add(const int* __restrict__ excl,
                                                const int* __restrict__ partials,
                                                const int* __restrict__ deg,
                                                int* __restrict__ row_start,
                                                int* __restrict__ cursor, int n) {
    int i = blockIdx.x * 256 + threadIdx.x;
    int v = excl[i] + partials[blockIdx.x];
    row_start[i] = v;
    cursor[i] = v;
    if (i == n - 1) row_start[n] = v + deg[i];
}

__global__ void csr_fill(const int* __restrict__ src, const int* __restrict__ dst,
                         int* __restrict__ cursor, int* __restrict__ eidx, int E) {
    int e = blockIdx.x * blockDim.x + threadIdx.x;
    if (e < E) {
        int pos = atomicAdd(&cursor[dst[e]], 1);
        eidx[pos] = src[e];
    }
}

// ---------------- weight transpose+cvt ----------------

__global__ void transpose_cvt(const float* __restrict__ W, unsigned short* __restrict__ Wt,
                              int K, int N) {
    int i = blockIdx.x * 256 + threadIdx.x;
    if (i < N * K) {
        int n = i / K, k = i - n * K;
        Wt[i] = f2bf(W[(size_t)k * N + n]);
    }
}

// ---------------- bf16 MFMA GEMM: C = A[M,K] @ Bt[Nc,K]^T, bf16 output ----------------
// BK=64 double-buffered single-barrier K-loop (fewer, better-covered drains).
// LDS rows are 128B; quad-slot XOR swizzle qp = q ^ (row&7) (involution, both sides).
// AF32=1: A f32, row-scaled, cvt to bf16 in reg-staging. AF32=0: A bf16 via gload_lds.

#define TM 128
#define TN 128
#define TK 64
#define NXCD 8

template<int AF32>
__global__ __launch_bounds__(256) void gemm_bf16_mfma(
    const void* __restrict__ Ap, const unsigned short* __restrict__ Bt,
    const float* __restrict__ rowscale, unsigned short* __restrict__ Cb,
    int M, int K, int Nc)
{
    __shared__ unsigned short As[2][TM][TK];   // 2 x 16 KB
    __shared__ unsigned short Bs[2][TN][TK];   // 2 x 16 KB

    const int tid  = threadIdx.x;
    const int lane = tid & 63;
    const int wave = tid >> 6;
    const int wr = wave >> 1, wc = wave & 1;
    const int lrow = lane & 15;
    const int lkg  = lane >> 4;

    // ---- XCD swizzle: siblings sharing an A-panel run on the same XCD ----
    const int nwg = gridDim.x;                // divisible by 8
    const int per = nwg / NXCD;
    const int lin = blockIdx.x;
    const int newlin = (lin % NXCD) * per + lin / NXCD;
    const int ncb = Nc / TN;
    const int m0 = (newlin / ncb) * TM;
    const int n0 = (newlin % ncb) * TN;

    // gload_lds slot geometry: instr i covers slots s = i*256 + wave*64 + lane
    // slot s -> row = s>>3, phys quad = s&7, logical quad = (s&7) ^ (row&7)
    int srow[4], sq[4];
    #pragma unroll
    for (int i = 0; i < 4; ++i) {
        int s = i * 256 + wave * 64 + lane;
        srow[i] = s >> 3;
        sq[i] = (s & 7) ^ ((s >> 3) & 7);
    }

    char* AsB = (char*)&As[0][0][0];
    char* BsB = (char*)&Bs[0][0][0];

    const float* Af = (const float*)Ap;
    const unsigned short* Ab = (const unsigned short*)Ap;

    auto stageOp = [&](const unsigned short* G, int rc0, int kt, char* opBase, int buf) {
        const int k0 = kt * TK;
        #pragma unroll
        for (int i = 0; i < 4; ++i)
            gload16(G + (size_t)(rc0 + srow[i]) * K + k0 + sq[i] * 8,
                    opBase + buf * 16384 + (i * 256 + wave * 64) * 16);
    };

    // AF32 A reg-staging: thread owns rows rA, rA+64, f32 cols g*16..g*16+15
    const int rA = tid >> 2;
    const int g  = tid & 3;
    const int qp0 = (2 * g) ^ (rA & 7);       // phys quad for cols g*16..+7
    const int qp1 = (2 * g + 1) ^ (rA & 7);   // phys quad for cols g*16+8..+15
    float sc0 = 1.f, sc1 = 1.f;
    if (AF32) {
        sc0 = rowscale[m0 + rA];
        sc1 = rowscale[m0 + rA + 64];
    }
    float4 L[8];
    auto loadA = [&](int kt) {
        const float* p0 = Af + (size_t)(m0 + rA) * K + kt * TK + g * 16;
        const float* p1 = p0 + (size_t)64 * K;
        L[0] = *reinterpret_cast<const float4*>(p0);
        L[1] = *reinterpret_cast<const float4*>(p0 + 4);
        L[2] = *reinterpret_cast<const float4*>(p0 + 8);
        L[3] = *reinterpret_cast<const float4*>(p0 + 12);
        L[4] = *reinterpret_cast<const float4*>(p1);
        L[5] = *reinterpret_cast<const float4*>(p1 + 4);
        L[6] = *reinterpret_cast<const float4*>(p1 + 8);
        L[7] = *reinterpret_cast<const float4*>(p1 + 12);
    };
    auto writeA = [&](int buf) {
        short8 k0v, k1v;
        #pragma unroll
        for (int r = 0; r < 2; ++r) {
            const float sc = r ? sc1 : sc0;
            const float4 f0 = L[r * 4 + 0], f1 = L[r * 4 + 1];
            const float4 f2 = L[r * 4 + 2], f3 = L[r * 4 + 3];
            k0v[0] = (short)f2bf(f0.x * sc); k0v[1] = (short)f2bf(f0.y * sc);
            k0v[2] = (short)f2bf(f0.z * sc); k0v[3] = (short)f2bf(f0.w * sc);
            k0v[4] = (short)f2bf(f1.x * sc); k0v[5] = (short)f2bf(f1.y * sc);
            k0v[6] = (short)f2bf(f1.z * sc); k0v[7] = (short)f2bf(f1.w * sc);
            k1v[0] = (short)f2bf(f2.x * sc); k1v[1] = (short)f2bf(f2.y * sc);
            k1v[2] = (short)f2bf(f2.z * sc); k1v[3] = (short)f2bf(f2.w * sc);
            k1v[4] = (short)f2bf(f3.x * sc); k1v[5] = (short)f2bf(f3.y * sc);
            k1v[6] = (short)f2bf(f3.z * sc); k1v[7] = (short)f2bf(f3.w * sc);
            char* rowb = AsB + buf * 16384 + (rA + r * 64) * 128;
            *reinterpret_cast<short8*>(rowb + qp0 * 16) = k0v;
            *reinterpret_cast<short8*>(rowb + qp1 * 16) = k1v;
        }
    };

    f32x4 acc[4][4] = {};

    // prologue: tile 0 into buffer 0
    stageOp(Bt, n0, 0, BsB, 0);
    if (AF32) { loadA(0); writeA(0); }
    else       stageOp(Ab, m0, 0, AsB, 0);
    __syncthreads();

    const int nk = K / TK;
    for (int kt = 0; kt < nk; ++kt) {
        const int cur = kt & 1, nxt = cur ^ 1;

        if (kt + 1 < nk) {
            stageOp(Bt, n0, kt + 1, BsB, nxt);
            if (AF32) loadA(kt + 1);
            else      stageOp(Ab, m0, kt + 1, AsB, nxt);
        }

        #pragma unroll
        for (int ks = 0; ks < 2; ++ks) {
            short8 af[4], bfr[4];
            #pragma unroll
            for (int mi = 0; mi < 4; ++mi) {
                const int row = wr * 64 + mi * 16 + lrow;
                const int qp = (ks * 4 + lkg) ^ (lrow & 7);
                af[mi] = *reinterpret_cast<const short8*>(&As[cur][row][qp * 8]);
            }
            #pragma unroll
            for (int ni = 0; ni < 4; ++ni) {
                const int row = wc * 64 + ni * 16 + lrow;
                const int qp = (ks * 4 + lkg) ^ (lrow & 7);
                bfr[ni] = *reinterpret_cast<const short8*>(&Bs[cur][row][qp * 8]);
            }
            #pragma unroll
            for (int mi = 0; mi < 4; ++mi)
                #pragma unroll
                for (int ni = 0; ni < 4; ++ni)
                    acc[mi][ni] = __builtin_amdgcn_mfma_f32_16x16x32_bf16(
                        af[mi], bfr[ni], acc[mi][ni], 0, 0, 0);
        }

        if (AF32 && kt + 1 < nk) writeA(nxt);

        __syncthreads();   // single barrier per K-step
    }

    #pragma unroll
    for (int mi = 0; mi < 4; ++mi)
        #pragma unroll
        for (int ni = 0; ni < 4; ++ni)
            #pragma unroll
            for (int r = 0; r < 4; ++r)
                Cb[(size_t)(m0 + wr * 64 + mi * 16 + (lane >> 4) * 4 + r) * Nc
                   + (n0 + wc * 64 + ni * 16 + lrow)] = f2bf(acc[mi][ni][r]);
}

// ---------------- CSR gather-aggregate (bf16 X), fused epilogues ----------------

template<int DIM, bool LAYER1>
__global__ __launch_bounds__(256) void aggregate(
    const int* __restrict__ row_start, const int* __restrict__ eidx,
    const unsigned short* __restrict__ Xb, const float* __restrict__ isi,
    const float* __restrict__ iso, const float* __restrict__ bias,
    unsigned short* __restrict__ out_bf, float* __restrict__ out_f)
{
    constexpr int F = DIM / 64;           // 8 (HID) or 4 (OUTD)
    using VecT = typename VecSel<F>::T;
    const int node = blockIdx.x * 4 + (threadIdx.x >> 6);
    const int lane = threadIdx.x & 63;

    const int beg = row_start[node];
    const int end = row_start[node + 1];
    const unsigned short* base = Xb + lane * F;

    float acc[F] = {};
    int e = beg;
    for (; e + 1 < end; e += 2) {
        int i0 = eidx[e], i1 = eidx[e + 1];
        VecT v0 = *reinterpret_cast<const VecT*>(base + (size_t)i0 * DIM);
        VecT v1 = *reinterpret_cast<const VecT*>(base + (size_t)i1 * DIM);
        #pragma unroll
        for (int f = 0; f < F; ++f) { acc[f] += bf2f(v0[f]); acc[f] += bf2f(v1[f]); }
    }
    if (e < end) {
        VecT v0 = *reinterpret_cast<const VecT*>(base + (size_t)eidx[e] * DIM);
        #pragma unroll
        for (int f = 0; f < F; ++f) acc[f] += bf2f(v0[f]);
    }

    const float si = isi[node];
    float bv[F];
    #pragma unroll
    for (int q = 0; q < F / 4; ++q)
        *reinterpret_cast<float4*>(&bv[q * 4]) =
            *reinterpret_cast<const float4*>(bias + lane * F + q * 4);

    if (LAYER1) {
        const float so = iso[node];
        short8 o;
        #pragma unroll
        for (int f = 0; f < F; ++f) {
            float v = acc[f] * si + bv[f];
            v = v > 0.f ? v : expm1f(v);
            o[f] = (short)f2bf(v * so);
        }
        *reinterpret_cast<short8*>(out_bf + (size_t)node * DIM + lane * F) = o;
    } else {
        #pragma unroll
        for (int q = 0; q < F / 4; ++q) {
            float4 v = make_float4(acc[q * 4 + 0] * si + bv[q * 4 + 0],
                                   acc[q * 4 + 1] * si + bv[q * 4 + 1],
                                   acc[q * 4 + 2] * si + bv[q * 4 + 2],
                                   acc[q * 4 + 3] * si + bv[q * 4 + 3]);
            *reinterpret_cast<float4*>(out_f + (size_t)node * DIM + lane * F + q * 4) = v;
        }
    }
}

// ---------------- launch ----------------

extern "C" void kernel_launch(void* const* d_in, const int* in_sizes, int n_in,
                              void* d_out, int out_size, void* d_ws, size_t ws_size,
                              hipStream_t stream) {
    const float* h  = (const float*)d_in[0];
    const float* W1 = (const float*)d_in[1];
    const float* b1 = (const float*)d_in[2];
    const float* W2 = (const float*)d_in[3];
    const float* b2 = (const float*)d_in[4];
    const int*   src = (const int*)d_in[5];
    const int*   dst = (const int*)d_in[6];

    const int N = in_sizes[0] / IN_DIM;   // 65536
    const int E = in_sizes[5];            // 524288
    float* out = (float*)d_out;

    // ---- workspace layout ----
    int* dego      = (int*)d_ws;                   // N
    int* degi      = dego + N;                     // N
    int* excl      = degi + N;                     // N
    int* partials  = excl + N;                     // 256
    int* row_start = partials + 256;               // N+1 (pad to N+64)
    int* cursor    = row_start + N + 64;           // N
    int* eidx      = cursor + N;                   // E
    float* iso     = (float*)(eidx + E);           // N
    float* isi     = iso + N;                      // N
    unsigned short* W1t = (unsigned short*)(isi + N);      // IN_DIM*HID
    unsigned short* W2t = W1t + (size_t)IN_DIM * HID;      // HID*OUTD
    unsigned short* X1b = W2t + (size_t)HID * OUTD;        // N*HID bf16 (67MB)
    unsigned short* X2b = X1b;                             // alias (X1 dead before gemm2 write)
    unsigned short* R2h = X1b + (size_t)N * HID;           // N*HID bf16 (67MB) — x1s

    hipMemsetAsync(dego, 0, sizeof(int) * (size_t)2 * N, stream);

    deg_kernel<<<(E + 255) / 256, 256, 0, stream>>>(src, dst, dego, degi, E);
    invsqrt_kernel<<<(N + 255) / 256, 256, 0, stream>>>(dego, degi, iso, isi, N);

    // CSR by dst
    scan_block<<<N / 256, 256, 0, stream>>>(degi, excl, partials);
    scan_partials<<<1, 256, 0, stream>>>(partials);
    scan_add<<<N / 256, 256, 0, stream>>>(excl, partials, degi, row_start, cursor, N);
    csr_fill<<<(E + 255) / 256, 256, 0, stream>>>(src, dst, cursor, eidx, E);

    // weights -> bf16 transposed
    transpose_cvt<<<(IN_DIM * HID + 255) / 256, 256, 0, stream>>>(W1, W1t, IN_DIM, HID);
    transpose_cvt<<<(HID * OUTD + 255) / 256, 256, 0, stream>>>(W2, W2t, HID, OUTD);

    // Layer 1: X1b = bf16((iso⊙h) @ W1)  [scale+cvt fused into A-staging]
    gemm_bf16_mfma<1><<<(N / TM) * (HID / TN), 256, 0, stream>>>(
        h, W1t, iso, X1b, N, IN_DIM, HID);
    aggregate<HID, true><<<N / 4, 256, 0, stream>>>(
        row_start, eidx, X1b, isi, iso, b1, R2h, nullptr);

    // Layer 2: X2b = bf16(R2h @ W2) ; out = agg(X2b)*isi + b2
    gemm_bf16_mfma<0><<<(N / TM) * (OUTD / TN), 256, 0, stream>>>(
        R2h, W2t, nullptr, X2b, N, HID, OUTD);
    aggregate<OUTD, false><<<N / 4, 256, 0, stream>>>(
        row_start, eidx, X2b, isi, iso, b2, nullptr, out);
}